// Round 10
// baseline (550.535 us; speedup 1.0000x reference)
//
#include <hip/hip_runtime.h>
#include <math.h>

typedef unsigned short u16;
typedef __attribute__((ext_vector_type(8))) short short8;
typedef __attribute__((ext_vector_type(4))) float f32x4;

#define AS1C(p) ((const __attribute__((address_space(1))) void*)(p))
#define AS3(p)  ((__attribute__((address_space(3))) void*)(p))

static __device__ __forceinline__ float b2f(u16 h) {
    union { unsigned u; float f; } c; c.u = ((unsigned)h) << 16; return c.f;
}
static __device__ __forceinline__ u16 f2b(float f) {
    union { float f; unsigned u; } c; c.f = f;
    unsigned r = c.u + 0x7FFFu + ((c.u >> 16) & 1u);
    return (u16)(r >> 16);
}

// Epilogue modes (runtime)
#define EP_NONE     0
#define EP_RELU     1
#define EP_SIGMOID  2
#define EP_TANH_MUL 3
#define EP_TANH_ADD 4
#define EP_DIAG     5

struct GDesc {
    const u16* A;
    const u16* W;
    const float* bias;
    const float* auxf;
    u16* outb;
    float* outf;
    int lda, ldd, N, K, ep, nbm;
};

struct GArgs { GDesc d0, d1, d2; int s1, s2; };

// 256x256 tile, BK=64, 512 threads = 8 waves. Deep double-buffer pipeline:
// per K-tile t:  barrier(a)  [t-1's readers of buf^1 done]
//                STAGE all 8 half-tile loads of t+1 -> buf^1
//                vmcnt(8) [tile t's loads, issued one full K-tile ago, landed]
//                barrier(b) [published]
//                free-run: READ A0,B0; MFMA q00; READ B1; MFMA q01;
//                          READ A1; MFMA q11; MFMA q10   (no mid-tile syncs)
// => 1 vmcnt + 2 barriers per K-tile; staged loads get a full K-tile (~2.5k cyc)
// of flight >> HBM latency. Frag rows: A: mh*128+wr*64+mm*16+(lane&15);
// B: nh*128+wc*32+nn*16+(lane&15). All ds_read addresses precomputed (imm
// offsets; K-loop unrolled x2 for static buffer choice). LDS swizzle (16B
// slot ^= row&7) on pre-swizzled global source + swizzled read pointers
// (zero conflicts, R4-R9 proven). REQUIRES K%64==0 and nkt even.
__global__ __launch_bounds__(512, 2)
void gemm_v3(GArgs ga)
{
    __shared__ __align__(16) u16 LDS[65536];   // buf d: A u16[d*32768,+16384) B +16384

    const int bid = (int)blockIdx.x;
    GDesc dd = (bid < ga.s1) ? ga.d0 : ((bid < ga.s2) ? ga.d1 : ga.d2);
    const int b = bid - ((bid < ga.s1) ? 0 : ((bid < ga.s2) ? ga.s1 : ga.s2));

    const int tid  = threadIdx.x;
    const int lane = tid & 63;
    const int wid  = tid >> 6;
    const int wr   = wid >> 2;          // 0..1
    const int wc   = wid & 3;           // 0..3

    const int bm = b % dd.nbm;
    const int bn = b / dd.nbm;
    const int lda = dd.lda, K = dd.K, N = dd.N, ldd = dd.ldd;
    const int nkt = K >> 6;

    // staging coords (pre-swizzled global source, linear LDS dest)
    const int srow  = tid >> 3;
    const int sslot = tid & 7;
    const int sgcol = (sslot ^ (srow & 7)) * 8;
    const u16* Ag = dd.A + (size_t)(bm * 256 + srow) * lda + sgcol;
    const u16* Wg = dd.W + (size_t)(bn * 256 + srow) * K + sgcol;
    const int ldst = tid * 8;

    f32x4 acc[8][4];
#pragma unroll
    for (int m = 0; m < 8; ++m)
#pragma unroll
        for (int n = 0; n < 4; ++n) acc[m][n] = (f32x4){0.f, 0.f, 0.f, 0.f};

    // ---- precomputed ds_read pointers (u16 units; frag row ≡ lane&7 mod 8)
    const int swz  = (lane & 7) << 4;
    const int cnat = (lane >> 4) << 4;
    const int aRow = (wr * 64 + (lane & 15)) * 64;
    const int bRow = (wc * 32 + (lane & 15)) * 64;
    const u16* pA00 = LDS + aRow + ((cnat ^ swz) >> 1);
    const u16* pA10 = LDS + aRow + ((((64) | cnat) ^ swz) >> 1);
    const u16* pA01 = pA00 + 32768;
    const u16* pA11 = pA10 + 32768;
    const u16* pB00 = LDS + 16384 + bRow + ((cnat ^ swz) >> 1);
    const u16* pB10 = LDS + 16384 + bRow + ((((64) | cnat) ^ swz) >> 1);
    const u16* pB01 = pB00 + 32768;
    const u16* pB11 = pB10 + 32768;

    short8 A0f[4][2], A1f[4][2], B0f[2][2], B1f[2][2];

    // A: row = mh*128 + wr*64 + mm*16 + (lane&15) -> u16 off mh*8192 + mm*1024
#define READ_A(AF, PK0, PK1, MHOFF)                                              \
    {                                                                            \
        _Pragma("unroll")                                                        \
        for (int mm = 0; mm < 4; ++mm) {                                         \
            AF[mm][0] = *(const short8*)((PK0) + (MHOFF) + mm * 1024);           \
            AF[mm][1] = *(const short8*)((PK1) + (MHOFF) + mm * 1024);           \
        }                                                                        \
    }
    // B: row = nh*128 + wc*32 + nn*16 + (lane&15) -> u16 off nh*8192 + nn*1024
#define READ_B(BF, PK0, PK1, NHOFF)                                              \
    {                                                                            \
        _Pragma("unroll")                                                        \
        for (int nn = 0; nn < 2; ++nn) {                                         \
            BF[nn][0] = *(const short8*)((PK0) + (NHOFF) + nn * 1024);           \
            BF[nn][1] = *(const short8*)((PK1) + (NHOFF) + nn * 1024);           \
        }                                                                        \
    }

#define STAGE_ALL(bufi, k0_)                                                     \
    {                                                                            \
        u16* al_ = &LDS[(bufi) * 32768 + ldst];                                  \
        u16* bl_ = &LDS[(bufi) * 32768 + 16384 + ldst];                          \
        _Pragma("unroll")                                                        \
        for (int j = 0; j < 4; ++j)                                              \
            __builtin_amdgcn_global_load_lds(AS1C(Ag + (size_t)(j * 64) * lda + (k0_)), \
                                             AS3(al_ + j * 4096), 16, 0, 0);     \
        _Pragma("unroll")                                                        \
        for (int j = 0; j < 4; ++j)                                              \
            __builtin_amdgcn_global_load_lds(AS1C(Wg + (size_t)(j * 64) * K + (k0_)),   \
                                             AS3(bl_ + j * 4096), 16, 0, 0);     \
    }

#define QMFMA(AF, BF, mh, nh)                                                    \
    {                                                                            \
        __builtin_amdgcn_s_setprio(1);                                           \
        _Pragma("unroll")                                                        \
        for (int mm = 0; mm < 4; ++mm)                                           \
            _Pragma("unroll")                                                    \
            for (int nn = 0; nn < 2; ++nn)                                       \
                _Pragma("unroll")                                                \
                for (int ks = 0; ks < 2; ++ks)                                   \
                    acc[(mh) * 4 + mm][(nh) * 2 + nn] =                          \
                        __builtin_amdgcn_mfma_f32_16x16x32_bf16(                 \
                            AF[mm][ks], BF[nn][ks], acc[(mh) * 4 + mm][(nh) * 2 + nn], 0, 0, 0); \
        __builtin_amdgcn_s_setprio(0);                                           \
    }

    // TILE: cur-buf ptrs CA0/CA1/CBp0/CBp1; stage into NBUF.
#define TILE(NBUF, CA0, CA1, CBp0, CBp1, ktv)                                    \
    {                                                                            \
        const int ka_ = ((ktv) + 1 < nkt) ? (ktv) + 1 : nkt - 1;                 \
        const int k0n = ka_ << 6;                                                \
        __builtin_amdgcn_s_barrier();          /* (a) buf^1 readers done */      \
        __builtin_amdgcn_sched_barrier(0);                                       \
        STAGE_ALL(NBUF, k0n);                                                    \
        __builtin_amdgcn_sched_barrier(0);                                       \
        asm volatile("s_waitcnt vmcnt(8)" ::: "memory");                         \
        __builtin_amdgcn_sched_barrier(0);                                       \
        __builtin_amdgcn_s_barrier();          /* (b) tile t published */        \
        __builtin_amdgcn_sched_barrier(0);                                       \
        READ_A(A0f, CA0, CA1, 0);                                                \
        READ_B(B0f, CBp0, CBp1, 0);                                              \
        QMFMA(A0f, B0f, 0, 0);                                                   \
        READ_B(B1f, CBp0, CBp1, 8192);                                           \
        QMFMA(A0f, B1f, 0, 1);                                                   \
        READ_A(A1f, CA0, CA1, 8192);                                             \
        QMFMA(A1f, B1f, 1, 1);                                                   \
        QMFMA(A1f, B0f, 1, 0);                                                   \
    }

    // ---- prologue: stage tile 0 into buf0; drain; publish
    STAGE_ALL(0, 0);
    __builtin_amdgcn_sched_barrier(0);
    asm volatile("s_waitcnt vmcnt(0)" ::: "memory");
    __builtin_amdgcn_sched_barrier(0);
    __builtin_amdgcn_s_barrier();
    __builtin_amdgcn_sched_barrier(0);

    for (int kt = 0; kt < nkt; kt += 2) {
        TILE(1, pA00, pA10, pB00, pB10, kt);
        TILE(0, pA01, pA11, pB01, pB11, kt + 1);
    }

#undef READ_A
#undef READ_B
#undef STAGE_ALL
#undef QMFMA
#undef TILE

    // epilogue: frag (m,n): R = bm*256+(m>>2)*128+wr*64+(m&3)*16+(lane>>4)*4+j
    //                       C = bn*256+(n>>1)*128+wc*32+(n&1)*16+(lane&15)
    const int ep = dd.ep;
#pragma unroll
    for (int n = 0; n < 4; ++n) {
        const int C = bn * 256 + (n >> 1) * 128 + wc * 32 + (n & 1) * 16 + (lane & 15);
        const float bv = dd.bias ? dd.bias[C] : 0.f;
#pragma unroll
        for (int m = 0; m < 8; ++m) {
            const int R0 = bm * 256 + (m >> 2) * 128 + wr * 64 + (m & 3) * 16 + ((lane >> 4) << 2);
#pragma unroll
            for (int j = 0; j < 4; ++j) {
                const int R = R0 + j;
                float v = acc[m][n][j] + bv;
                if (ep == EP_RELU)          v = fmaxf(v, 0.f);
                else if (ep == EP_SIGMOID)  v = 1.f / (1.f + expf(-v));
                else if (ep == EP_TANH_MUL) v = tanhf(v) * dd.auxf[(size_t)R * N + C];
                else if (ep == EP_TANH_ADD) v = dd.auxf[(size_t)R * N + C] + tanhf(v);
                else if (ep == EP_DIAG)     { if (R == C) v += 0.9f * tanhf(dd.auxf[R]); }
                dd.outb[(size_t)R * ldd + C] = f2b(v);
                if (dd.outf) dd.outf[(size_t)R * N + C] = v;
            }
        }
    }
}

// In-place LayerNorm over D=1024 bf16 (+optional ReLU). gam/bet fp32.
template<bool RELU>
__global__ __launch_bounds__(256)
void ln1024(u16* __restrict__ X, const float* __restrict__ gam, const float* __restrict__ bet)
{
    const int row = blockIdx.x;
    u16* xp = X + (size_t)row * 1024 + threadIdx.x * 4;
    u16 loc[4];
    *(uint2*)loc = *(const uint2*)xp;
    float x0 = b2f(loc[0]), x1 = b2f(loc[1]), x2 = b2f(loc[2]), x3 = b2f(loc[3]);
    float s = x0 + x1 + x2 + x3;
    float q = x0 * x0 + x1 * x1 + x2 * x2 + x3 * x3;
#pragma unroll
    for (int off = 32; off; off >>= 1) { s += __shfl_xor(s, off); q += __shfl_xor(q, off); }
    __shared__ float sm[8];
    const int wave = threadIdx.x >> 6, lane = threadIdx.x & 63;
    if (lane == 0) { sm[wave] = s; sm[4 + wave] = q; }
    __syncthreads();
    s = sm[0] + sm[1] + sm[2] + sm[3];
    q = sm[4] + sm[5] + sm[6] + sm[7];
    const float mean = s * (1.f / 1024.f);
    const float var  = q * (1.f / 1024.f) - mean * mean;
    const float inv  = rsqrtf(var + 1e-5f);
    const int cb = threadIdx.x * 4;
#pragma unroll
    for (int j = 0; j < 4; ++j) {
        float y = (b2f(loc[j]) - mean) * inv * gam[cb + j] + bet[cb + j];
        if (RELU) y = fmaxf(y, 0.f);
        loc[j] = f2b(y);
    }
    *(uint2*)xp = *(uint2*)loc;
}

// s_t = LN(s_prev + g*pm + (1-g)*wm) over D=1024. sp fp32, g/pm/wm bf16, out fp32.
__global__ __launch_bounds__(256)
void mix_ln(const float* __restrict__ sp, const u16* __restrict__ gt,
            const u16* __restrict__ pm, const u16* __restrict__ wm,
            const float* __restrict__ og, const float* __restrict__ ob,
            float* __restrict__ out)
{
    const int row = blockIdx.x;
    const size_t base = (size_t)row * 1024 + threadIdx.x * 4;
    float4 lsp = *(const float4*)(sp + base);
    u16 lg[4], lp[4], lw[4];
    *(uint2*)lg = *(const uint2*)(gt + base);
    *(uint2*)lp = *(const uint2*)(pm + base);
    *(uint2*)lw = *(const uint2*)(wm + base);
    float x[4];
    const float* lspp = (const float*)&lsp;
#pragma unroll
    for (int j = 0; j < 4; ++j) {
        float g = b2f(lg[j]);
        x[j] = lspp[j] + g * b2f(lp[j]) + (1.f - g) * b2f(lw[j]);
    }
    float s = x[0] + x[1] + x[2] + x[3];
    float q = x[0]*x[0] + x[1]*x[1] + x[2]*x[2] + x[3]*x[3];
#pragma unroll
    for (int off = 32; off; off >>= 1) { s += __shfl_xor(s, off); q += __shfl_xor(q, off); }
    __shared__ float sm[8];
    const int wave = threadIdx.x >> 6, lane = threadIdx.x & 63;
    if (lane == 0) { sm[wave] = s; sm[4 + wave] = q; }
    __syncthreads();
    s = sm[0] + sm[1] + sm[2] + sm[3];
    q = sm[4] + sm[5] + sm[6] + sm[7];
    const float mean = s * (1.f / 1024.f);
    const float var  = q * (1.f / 1024.f) - mean * mean;
    const float inv  = rsqrtf(var + 1e-5f);
    const int cb = threadIdx.x * 4;
    float4 o;
    float* op = (float*)&o;
#pragma unroll
    for (int j = 0; j < 4; ++j)
        op[j] = (x[j] - mean) * inv * og[cb + j] + ob[cb + j];
    *(float4*)(out + base) = o;
}

// Batched strided copy/convert: fp32->bf16 or bf16->bf16, 8 elems/thread.
struct CDesc { const void* src; u16* dst; int srcCols8; int dstStride; int dstOff; unsigned end; int isbf16; };
struct CArgs { CDesc d[16]; unsigned total; };

__global__ __launch_bounds__(256)
void multi_copy(CArgs ca)
{
    const unsigned idx = blockIdx.x * 256 + threadIdx.x;
    if (idx >= ca.total) return;
    int i = 0; unsigned start = 0;
    while (idx >= ca.d[i].end) { start = ca.d[i].end; ++i; }
    const CDesc cd = ca.d[i];
    const unsigned local = idx - start;
    const int r = local / cd.srcCols8;
    const int c = local % cd.srcCols8;
    u16 o[8];
    if (cd.isbf16) {
        *(uint4*)o = *(const uint4*)((const u16*)cd.src + ((size_t)r * cd.srcCols8 + c) * 8);
    } else {
        const float* s = (const float*)cd.src + ((size_t)r * cd.srcCols8 + c) * 8;
        const float4 a = *(const float4*)s;
        const float4 bq = *(const float4*)(s + 4);
        const float* ap = (const float*)&a;
        const float* bp = (const float*)&bq;
#pragma unroll
        for (int j = 0; j < 4; ++j) { o[j] = f2b(ap[j]); o[4 + j] = f2b(bp[j]); }
    }
    *(uint4*)(cd.dst + (size_t)r * cd.dstStride + cd.dstOff + (size_t)c * 8) = *(uint4*)o;
}

extern "C" void kernel_launch(void* const* d_in, const int* in_sizes, int n_in,
                              void* d_out, int out_size, void* d_ws, size_t ws_size,
                              hipStream_t stream)
{
    const float* s_prev = (const float*)d_in[0];
    const float* w_prev = (const float*)d_in[1];
    const float* p_prev = (const float*)d_in[2];
    const float* e_t    = (const float*)d_in[3];
    const float* c_t    = (const float*)d_in[4];
    const float* fw1    = (const float*)d_in[5];
    const float* fb1    = (const float*)d_in[6];
    const float* fln_g  = (const float*)d_in[7];
    const float* fln_b  = (const float*)d_in[8];
    const float* fw2    = (const float*)d_in[9];
    const float* fb2    = (const float*)d_in[10];
    const float* A_diag = (const float*)d_in[11];
    const float* A_U    = (const float*)d_in[12];
    const float* A_V    = (const float*)d_in[13];
    const float* amod_w = (const float*)d_in[14];
    const float* amod_b = (const float*)d_in[15];
    const float* bnet_w = (const float*)d_in[16];
    const float* bnet_b = (const float*)d_in[17];
    const float* pw1    = (const float*)d_in[18];
    const float* pb1    = (const float*)d_in[19];
    const float* pln_g  = (const float*)d_in[20];
    const float* pln_b  = (const float*)d_in[21];
    const float* pw2    = (const float*)d_in[22];
    const float* pb2    = (const float*)d_in[23];
    const float* pw3    = (const float*)d_in[24];
    const float* pb3    = (const float*)d_in[25];
    const float* gw     = (const float*)d_in[26];
    const float* gb     = (const float*)d_in[27];
    const float* uw     = (const float*)d_in[28];
    const float* up     = (const float*)d_in[29];
    const float* oln_g  = (const float*)d_in[30];
    const float* oln_b  = (const float*)d_in[31];

    float* out_s = (float*)d_out;
    float* out_w = out_s + (size_t)8192 * 1024;
    float* out_p = out_w + (size_t)8192 * 1024;

    u16* ws = (u16*)d_ws;
    u16* FIN  = ws;
    u16* W_bf = ws + 12582912;
    u16* H    = ws + 20971520;
    u16* P_bf = H;
    u16* Z    = ws + 29360128;
    u16* G    = ws + 33554432;
    u16* ACAT = ws + 41943040;
    u16* PM   = ACAT;
    u16* WM   = ACAT + 8388608;
    u16* WCAT = ws + 58720256;
    u16* wb   = ws + 60817408;
    u16* fw1b  = wb;
    u16* gwb   = wb + 2621440;
    u16* fw2b  = wb + 5242880;
    u16* amodb = wb + 5767168;
    u16* pw1b  = wb + 6291456;
    u16* pw2b  = wb + 7864320;
    u16* pw3b  = wb + 8388608;
    u16* uwb   = wb + 8650752;
    u16* upb   = wb + 9699328;
    u16* AUb   = wb + 10223616;
    u16* AVb   = wb + 10485760;

    const dim3 blk(256);
    const dim3 blk512(512);

    // ---------- batch 1
    {
        CArgs ca; unsigned cum = 0; int nd = 0;
        auto push = [&](const void* src, u16* dst, int cols8, int stride, int off,
                        int rows, int isbf) {
            cum += (unsigned)rows * cols8;
            ca.d[nd++] = CDesc{src, dst, cols8, stride, off, cum, isbf};
        };
        push(fw1,    fw1b,  320, 2560, 0,    1024, 0);
        push(gw,     gwb,   320, 2560, 0,    1024, 0);
        push(fw2,    fw2b,  128, 1024, 0,    512,  0);
        push(amod_w, amodb, 64,  512,  0,    1024, 0);
        push(pw1,    pw1b,  192, 1536, 0,    1024, 0);
        push(pw2,    pw2b,  128, 1024, 0,    512,  0);
        push(pw3,    pw3b,  64,  512,  0,    512,  0);
        push(uw,     uwb,   128, 1024, 0,    1024, 0);
        push(up,     upb,   64,  512,  0,    1024, 0);
        push(A_U,    AUb,   32,  256,  0,    1024, 0);
        push(A_V,    AVb,   32,  256,  0,    1024, 0);
        push(s_prev, FIN,   128, 2560, 0,    8192, 0);
        push(e_t,    FIN,   128, 2560, 1024, 8192, 0);
        push(c_t,    FIN,   64,  2560, 2048, 8192, 0);
        push(c_t,    ACAT,  64,  2048, 1024, 8192, 0);
        push(bnet_w, WCAT,  128, 2048, 1024, 1024, 0);
        ca.total = cum;
        multi_copy<<<dim3((cum + 255) / 256), blk, 0, stream>>>(ca);
    }

    // ---------- fused GEMM 1: fw1 (H) || gate (G) -> 256 blocks
    {
        GArgs ga;
        ga.d0 = GDesc{FIN, fw1b, fb1, nullptr, H, nullptr, 2560, 1024, 1024, 2560, EP_NONE,    32};
        ga.d1 = GDesc{FIN, gwb,  gb,  nullptr, G, nullptr, 2560, 1024, 1024, 2560, EP_SIGMOID, 32};
        ga.d2 = ga.d1; ga.s1 = 128; ga.s2 = 256;
        gemm_v3<<<dim3(256), blk512, 0, stream>>>(ga);
    }
    ln1024<true><<<8192, blk, 0, stream>>>(H, fln_g, fln_b);

    // ---------- fused GEMM 2: fw2 (Z) || amod (ACAT) || A_base (WCAT) -> 208 blocks
    {
        GArgs ga;
        ga.d0 = GDesc{H,          fw2b,  fb2,     nullptr, Z,    nullptr, 1024, 512,  512,  1024, EP_NONE,     32};
        ga.d1 = GDesc{FIN + 2048, amodb, amod_b,  w_prev,  ACAT, nullptr, 2560, 2048, 1024, 512,  EP_TANH_MUL, 32};
        ga.d2 = GDesc{AUb,        AVb,   nullptr, A_diag,  WCAT, nullptr, 256,  2048, 1024, 256,  EP_DIAG,     4};
        ga.s1 = 64; ga.s2 = 192;
        gemm_v3<<<dim3(208), blk512, 0, stream>>>(ga);
    }

    // ---------- batch 2
    {
        CArgs ca; unsigned cum = 0; int nd = 0;
        auto push = [&](const void* src, u16* dst, int cols8, int stride, int off,
                        int rows, int isbf) {
            cum += (unsigned)rows * cols8;
            ca.d[nd++] = CDesc{src, dst, cols8, stride, off, cum, isbf};
        };
        push(p_prev, FIN,  64, 1536, 0,    8192, 0);
        push(Z,      FIN,  64, 1536, 512,  8192, 1);
        push(c_t,    FIN,  64, 1536, 1024, 8192, 0);
        push(Z,      ACAT, 64, 2048, 1536, 8192, 1);
        ca.total = cum;
        multi_copy<<<dim3((cum + 255) / 256), blk, 0, stream>>>(ca);
    }

    // ---------- fused GEMM 3: w_t (ACAT@WCAT^T) || pw1 (PIN) -> 256 blocks
    {
        GArgs ga;
        ga.d0 = GDesc{ACAT, WCAT, bnet_b, nullptr, W_bf, out_w,   2048, 1024, 1024, 2048, EP_NONE, 32};
        ga.d1 = GDesc{FIN,  pw1b, pb1,    nullptr, H,    nullptr, 1536, 1024, 1024, 1536, EP_NONE, 32};
        ga.d2 = ga.d1; ga.s1 = 128; ga.s2 = 256;
        gemm_v3<<<dim3(256), blk512, 0, stream>>>(ga);
    }
    ln1024<true><<<8192, blk, 0, stream>>>(H, pln_g, pln_b);

    // ---------- fused GEMM 4: pw2 (H -> Z, relu) || uw (W_bf -> WM) -> 192 blocks
    {
        GArgs ga;
        ga.d0 = GDesc{H,    pw2b, pb2,     nullptr, Z,  nullptr, 1024, 512,  512,  1024, EP_RELU, 32};
        ga.d1 = GDesc{W_bf, uwb,  nullptr, nullptr, WM, nullptr, 1024, 1024, 1024, 1024, EP_NONE, 32};
        ga.d2 = ga.d1; ga.s1 = 64; ga.s2 = 192;
        gemm_v3<<<dim3(192), blk512, 0, stream>>>(ga);
    }

    // ---------- pw3
    {
        GArgs ga;
        ga.d0 = GDesc{Z, pw3b, pb3, p_prev, P_bf, out_p, 512, 512, 512, 512, EP_TANH_ADD, 32};
        ga.d1 = ga.d0; ga.d2 = ga.d0; ga.s1 = 64; ga.s2 = 64;
        gemm_v3<<<dim3(64), blk512, 0, stream>>>(ga);
    }

    // ---------- up
    {
        GArgs ga;
        ga.d0 = GDesc{P_bf, upb, nullptr, nullptr, PM, nullptr, 512, 1024, 1024, 512, EP_NONE, 32};
        ga.d1 = ga.d0; ga.d2 = ga.d0; ga.s1 = 128; ga.s2 = 128;
        gemm_v3<<<dim3(128), blk512, 0, stream>>>(ga);
    }

    mix_ln<<<8192, blk, 0, stream>>>(s_prev, G, PM, WM, oln_g, oln_b, out_s);
}

// Round 11
// 527.624 us; speedup vs baseline: 1.0434x; 1.0434x over previous
//
#include <hip/hip_runtime.h>
#include <math.h>

typedef unsigned short u16;
typedef __attribute__((ext_vector_type(8))) short short8;
typedef __attribute__((ext_vector_type(4))) float f32x4;

#define AS1C(p) ((const __attribute__((address_space(1))) void*)(p))
#define AS3(p)  ((__attribute__((address_space(3))) void*)(p))

static __device__ __forceinline__ float b2f(u16 h) {
    union { unsigned u; float f; } c; c.u = ((unsigned)h) << 16; return c.f;
}
static __device__ __forceinline__ u16 f2b(float f) {
    union { float f; unsigned u; } c; c.f = f;
    unsigned r = c.u + 0x7FFFu + ((c.u >> 16) & 1u);
    return (u16)(r >> 16);
}

// Epilogue modes (runtime)
#define EP_NONE     0
#define EP_RELU     1
#define EP_SIGMOID  2
#define EP_TANH_MUL 3
#define EP_TANH_ADD 4
#define EP_DIAG     5

struct GDesc {
    const u16* A;
    const u16* W;
    const float* bias;
    const float* auxf;
    u16* outb;
    float* outf;
    int lda, ldd, N, K, ep, nbm;
};

struct GArgs { GDesc d0, d1, d2; int s1, s2; };

// 256x256 tile, BK=64, 512 threads = 8 waves (wr 0..1 x wc 0..3, wave-out
// 64x32 per quadrant; quadrant (mh,nh) = rows[mh*128,+128) x cols[nh*128,+128)).
// m201-style 4-phase K-tile schedule:
//   phase = [own ds_reads (12/4/8/0 b128)] [stage 1 half-tile (2 gload_lds)]
//           [vmcnt(6)] [s_barrier] [lgkmcnt(0)] [setprio(1) 16 MFMA setprio(0)]
//           [closing s_barrier]
// Stage stream per tile t: B0(t+1), B1(t+1), A1(t+1), A0(t+2 -> CURRENT buf,
// region free since ph1's closing barrier). Constant 3-half lead; uniform
// vmcnt(6) confirms exactly the half consumed next phase (ledger verified);
// closing barrier publishes cross-thread + makes region reuse safe.
// MFMA order q00,q01,q11,q10; frag reg sets A0f/A1f/B0f/B1f read once per tile.
// LDS swizzle (16B slot ^= row&7) on pre-swizzled global source + swizzled
// read pointers (zero conflicts R4-R10 proven). All ds_read addresses
// precomputed (8 pointers, imm offsets; K-loop unrolled x2 for static bufs).
// REQUIRES K%64==0 and nkt even.
__global__ __launch_bounds__(512, 2)
void gemm_v4(GArgs ga)
{
    __shared__ __align__(16) u16 LDS[65536];   // buf d: A u16[d*32768,+16384) B +16384

    const int bid = (int)blockIdx.x;
    GDesc dd = (bid < ga.s1) ? ga.d0 : ((bid < ga.s2) ? ga.d1 : ga.d2);
    const int b = bid - ((bid < ga.s1) ? 0 : ((bid < ga.s2) ? ga.s1 : ga.s2));

    const int tid  = threadIdx.x;
    const int lane = tid & 63;
    const int wid  = tid >> 6;
    const int wr   = wid >> 2;          // 0..1
    const int wc   = wid & 3;           // 0..3

    const int bm = b % dd.nbm;
    const int bn = b / dd.nbm;
    const int lda = dd.lda, K = dd.K, N = dd.N, ldd = dd.ldd;
    const int nkt = K >> 6;

    // staging coords (pre-swizzled global source, linear LDS dest)
    const int srow  = tid >> 3;
    const int sslot = tid & 7;
    const int sgcol = (sslot ^ (srow & 7)) * 8;
    const u16* Ag = dd.A + (size_t)(bm * 256 + srow) * lda + sgcol;
    const u16* Wg = dd.W + (size_t)(bn * 256 + srow) * K + sgcol;
    const int ldst = tid * 8;

    f32x4 acc[8][4];
#pragma unroll
    for (int m = 0; m < 8; ++m)
#pragma unroll
        for (int n = 0; n < 4; ++n) acc[m][n] = (f32x4){0.f, 0.f, 0.f, 0.f};

    // ---- precomputed ds_read pointers (u16 units; frag row ≡ lane&7 mod 8)
    const int swz  = (lane & 7) << 4;
    const int cnat = (lane >> 4) << 4;
    const int aRow = (wr * 64 + (lane & 15)) * 64;      // quadrant-local A row
    const int bRow = (wc * 32 + (lane & 15)) * 64;      // quadrant-local B row
    const u16* pA00 = LDS + aRow + ((cnat ^ swz) >> 1);            // buf0 ks0
    const u16* pA10 = LDS + aRow + ((((64) | cnat) ^ swz) >> 1);   // buf0 ks1
    const u16* pA01 = pA00 + 32768;                                // buf1
    const u16* pA11 = pA10 + 32768;
    const u16* pB00 = LDS + 16384 + bRow + ((cnat ^ swz) >> 1);
    const u16* pB10 = LDS + 16384 + bRow + ((((64) | cnat) ^ swz) >> 1);
    const u16* pB01 = pB00 + 32768;
    const u16* pB11 = pB10 + 32768;

    short8 A0f[4][2], A1f[4][2], B0f[2][2], B1f[2][2];

    // A: row = mh*128 + wr*64 + mm*16 + (lane&15) -> u16 off mh*8192 + mm*1024
#define READ_A(AF, PK0, PK1, MHOFF)                                              \
    {                                                                            \
        _Pragma("unroll")                                                        \
        for (int mm = 0; mm < 4; ++mm) {                                         \
            AF[mm][0] = *(const short8*)((PK0) + (MHOFF) + mm * 1024);           \
            AF[mm][1] = *(const short8*)((PK1) + (MHOFF) + mm * 1024);           \
        }                                                                        \
    }
    // B: row = nh*128 + wc*32 + nn*16 + (lane&15) -> u16 off nh*8192 + nn*1024
#define READ_B(BF, PK0, PK1, NHOFF)                                              \
    {                                                                            \
        _Pragma("unroll")                                                        \
        for (int nn = 0; nn < 2; ++nn) {                                         \
            BF[nn][0] = *(const short8*)((PK0) + (NHOFF) + nn * 1024);           \
            BF[nn][1] = *(const short8*)((PK1) + (NHOFF) + nn * 1024);           \
        }                                                                        \
    }

#define STAGE_A(bufi, k0_, h)                                                    \
    {                                                                            \
        u16* d_ = &LDS[(bufi) * 32768 + ldst];                                   \
        _Pragma("unroll")                                                        \
        for (int j = 2 * (h); j < 2 * (h) + 2; ++j)                              \
            __builtin_amdgcn_global_load_lds(AS1C(Ag + (size_t)(j * 64) * lda + (k0_)), \
                                             AS3(d_ + j * 4096), 16, 0, 0);      \
    }
#define STAGE_B(bufi, k0_, h)                                                    \
    {                                                                            \
        u16* d_ = &LDS[(bufi) * 32768 + 16384 + ldst];                           \
        _Pragma("unroll")                                                        \
        for (int j = 2 * (h); j < 2 * (h) + 2; ++j)                              \
            __builtin_amdgcn_global_load_lds(AS1C(Wg + (size_t)(j * 64) * K + (k0_)),   \
                                             AS3(d_ + j * 4096), 16, 0, 0);      \
    }

    // mid-phase join: counted vmem wait + barrier + own-reads join
#define VWB()                                                                    \
    __builtin_amdgcn_sched_barrier(0);                                           \
    asm volatile("s_waitcnt vmcnt(6)" ::: "memory");                             \
    __builtin_amdgcn_sched_barrier(0);                                           \
    __builtin_amdgcn_s_barrier();                                                \
    asm volatile("s_waitcnt lgkmcnt(0)" ::: "memory");                           \
    __builtin_amdgcn_sched_barrier(0);

    // closing barrier: publishes this phase's reads-complete (lgkm0 ran) so a
    // later stage may overwrite the region
#define CLB()                                                                    \
    __builtin_amdgcn_sched_barrier(0);                                           \
    __builtin_amdgcn_s_barrier();                                                \
    __builtin_amdgcn_sched_barrier(0);

#define QMFMA(AF, BF, mh, nh)                                                    \
    {                                                                            \
        __builtin_amdgcn_s_setprio(1);                                           \
        _Pragma("unroll")                                                        \
        for (int mm = 0; mm < 4; ++mm)                                           \
            _Pragma("unroll")                                                    \
            for (int nn = 0; nn < 2; ++nn)                                       \
                _Pragma("unroll")                                                \
                for (int ks = 0; ks < 2; ++ks)                                   \
                    acc[(mh) * 4 + mm][(nh) * 2 + nn] =                          \
                        __builtin_amdgcn_mfma_f32_16x16x32_bf16(                 \
                            AF[mm][ks], BF[nn][ks], acc[(mh) * 4 + mm][(nh) * 2 + nn], 0, 0, 0); \
        __builtin_amdgcn_s_setprio(0);                                           \
    }

    // TILE reading buffer CBUF (ptrs CA0/CA1/CB0/CB1), staging B0,B1,A1 of
    // t+1 into NBUF and A0 of t+2 into CBUF.
#define TILE(CBUF, NBUF, CA0, CA1, CB0, CB1, k0n, k0nn)                          \
    {                                                                            \
        /* ph1: q00 */                                                           \
        READ_A(A0f, CA0, CA1, 0);                                                \
        READ_B(B0f, CB0, CB1, 0);                                                \
        STAGE_B(NBUF, k0n, 0);                                                   \
        VWB();                                                                   \
        QMFMA(A0f, B0f, 0, 0);                                                   \
        CLB();                                                                   \
        /* ph2: q01 */                                                           \
        READ_B(B1f, CB0, CB1, 8192);                                             \
        STAGE_B(NBUF, k0n, 1);                                                   \
        VWB();                                                                   \
        QMFMA(A0f, B1f, 0, 1);                                                   \
        CLB();                                                                   \
        /* ph3: q11 */                                                           \
        READ_A(A1f, CA0, CA1, 8192);                                             \
        STAGE_A(NBUF, k0n, 1);                                                   \
        VWB();                                                                   \
        QMFMA(A1f, B1f, 1, 1);                                                   \
        CLB();                                                                   \
        /* ph4: q10 (no reads; stage A0(t+2) into CURRENT buf) */                \
        STAGE_A(CBUF, k0nn, 0);                                                  \
        VWB();                                                                   \
        QMFMA(A1f, B0f, 1, 0);                                                   \
        CLB();                                                                   \
    }

    // ---- prologue: A0(t0),B0(t0),B1(t0),A1(t0) -> buf0; A0(t1) -> buf1
    {
        const int kp1 = ((nkt > 1) ? 1 : 0) << 6;
        STAGE_A(0, 0, 0);
        STAGE_B(0, 0, 0);
        STAGE_B(0, 0, 1);
        STAGE_A(0, 0, 1);
        STAGE_A(1, kp1, 0);
        __builtin_amdgcn_sched_barrier(0);
        asm volatile("s_waitcnt vmcnt(6)" ::: "memory");   // A0,B0(t0) landed
        __builtin_amdgcn_sched_barrier(0);
        __builtin_amdgcn_s_barrier();
        __builtin_amdgcn_sched_barrier(0);
    }

    for (int kt = 0; kt < nkt; kt += 2) {
        const int ka1 = ((kt + 1 < nkt) ? kt + 1 : nkt - 1) << 6;
        const int ka2 = ((kt + 2 < nkt) ? kt + 2 : nkt - 1) << 6;
        const int kb1 = ka2;
        const int kb2 = ((kt + 3 < nkt) ? kt + 3 : nkt - 1) << 6;
        TILE(0, 1, pA00, pA10, pB00, pB10, ka1, ka2);
        TILE(1, 0, pA01, pA11, pB01, pB11, kb1, kb2);
    }

#undef READ_A
#undef READ_B
#undef STAGE_A
#undef STAGE_B
#undef VWB
#undef CLB
#undef QMFMA
#undef TILE

    // epilogue: frag (m,n): R = bm*256+(m>>2)*128+wr*64+(m&3)*16+(lane>>4)*4+j
    //                       C = bn*256+(n>>1)*128+wc*32+(n&1)*16+(lane&15)
    const int ep = dd.ep;
#pragma unroll
    for (int n = 0; n < 4; ++n) {
        const int C = bn * 256 + (n >> 1) * 128 + wc * 32 + (n & 1) * 16 + (lane & 15);
        const float bv = dd.bias ? dd.bias[C] : 0.f;
#pragma unroll
        for (int m = 0; m < 8; ++m) {
            const int R0 = bm * 256 + (m >> 2) * 128 + wr * 64 + (m & 3) * 16 + ((lane >> 4) << 2);
#pragma unroll
            for (int j = 0; j < 4; ++j) {
                const int R = R0 + j;
                float v = acc[m][n][j] + bv;
                if (ep == EP_RELU)          v = fmaxf(v, 0.f);
                else if (ep == EP_SIGMOID)  v = 1.f / (1.f + expf(-v));
                else if (ep == EP_TANH_MUL) v = tanhf(v) * dd.auxf[(size_t)R * N + C];
                else if (ep == EP_TANH_ADD) v = dd.auxf[(size_t)R * N + C] + tanhf(v);
                else if (ep == EP_DIAG)     { if (R == C) v += 0.9f * tanhf(dd.auxf[R]); }
                dd.outb[(size_t)R * ldd + C] = f2b(v);
                if (dd.outf) dd.outf[(size_t)R * N + C] = v;
            }
        }
    }
}

// In-place LayerNorm over D=1024 bf16 (+optional ReLU). gam/bet fp32.
template<bool RELU>
__global__ __launch_bounds__(256)
void ln1024(u16* __restrict__ X, const float* __restrict__ gam, const float* __restrict__ bet)
{
    const int row = blockIdx.x;
    u16* xp = X + (size_t)row * 1024 + threadIdx.x * 4;
    u16 loc[4];
    *(uint2*)loc = *(const uint2*)xp;
    float x0 = b2f(loc[0]), x1 = b2f(loc[1]), x2 = b2f(loc[2]), x3 = b2f(loc[3]);
    float s = x0 + x1 + x2 + x3;
    float q = x0 * x0 + x1 * x1 + x2 * x2 + x3 * x3;
#pragma unroll
    for (int off = 32; off; off >>= 1) { s += __shfl_xor(s, off); q += __shfl_xor(q, off); }
    __shared__ float sm[8];
    const int wave = threadIdx.x >> 6, lane = threadIdx.x & 63;
    if (lane == 0) { sm[wave] = s; sm[4 + wave] = q; }
    __syncthreads();
    s = sm[0] + sm[1] + sm[2] + sm[3];
    q = sm[4] + sm[5] + sm[6] + sm[7];
    const float mean = s * (1.f / 1024.f);
    const float var  = q * (1.f / 1024.f) - mean * mean;
    const float inv  = rsqrtf(var + 1e-5f);
    const int cb = threadIdx.x * 4;
#pragma unroll
    for (int j = 0; j < 4; ++j) {
        float y = (b2f(loc[j]) - mean) * inv * gam[cb + j] + bet[cb + j];
        if (RELU) y = fmaxf(y, 0.f);
        loc[j] = f2b(y);
    }
    *(uint2*)xp = *(uint2*)loc;
}

// s_t = LN(s_prev + g*pm + (1-g)*wm) over D=1024. sp fp32, g/pm/wm bf16, out fp32.
__global__ __launch_bounds__(256)
void mix_ln(const float* __restrict__ sp, const u16* __restrict__ gt,
            const u16* __restrict__ pm, const u16* __restrict__ wm,
            const float* __restrict__ og, const float* __restrict__ ob,
            float* __restrict__ out)
{
    const int row = blockIdx.x;
    const size_t base = (size_t)row * 1024 + threadIdx.x * 4;
    float4 lsp = *(const float4*)(sp + base);
    u16 lg[4], lp[4], lw[4];
    *(uint2*)lg = *(const uint2*)(gt + base);
    *(uint2*)lp = *(const uint2*)(pm + base);
    *(uint2*)lw = *(const uint2*)(wm + base);
    float x[4];
    const float* lspp = (const float*)&lsp;
#pragma unroll
    for (int j = 0; j < 4; ++j) {
        float g = b2f(lg[j]);
        x[j] = lspp[j] + g * b2f(lp[j]) + (1.f - g) * b2f(lw[j]);
    }
    float s = x[0] + x[1] + x[2] + x[3];
    float q = x[0]*x[0] + x[1]*x[1] + x[2]*x[2] + x[3]*x[3];
#pragma unroll
    for (int off = 32; off; off >>= 1) { s += __shfl_xor(s, off); q += __shfl_xor(q, off); }
    __shared__ float sm[8];
    const int wave = threadIdx.x >> 6, lane = threadIdx.x & 63;
    if (lane == 0) { sm[wave] = s; sm[4 + wave] = q; }
    __syncthreads();
    s = sm[0] + sm[1] + sm[2] + sm[3];
    q = sm[4] + sm[5] + sm[6] + sm[7];
    const float mean = s * (1.f / 1024.f);
    const float var  = q * (1.f / 1024.f) - mean * mean;
    const float inv  = rsqrtf(var + 1e-5f);
    const int cb = threadIdx.x * 4;
    float4 o;
    float* op = (float*)&o;
#pragma unroll
    for (int j = 0; j < 4; ++j)
        op[j] = (x[j] - mean) * inv * og[cb + j] + ob[cb + j];
    *(float4*)(out + base) = o;
}

// Batched strided copy/convert: fp32->bf16 or bf16->bf16, 8 elems/thread.
struct CDesc { const void* src; u16* dst; int srcCols8; int dstStride; int dstOff; unsigned end; int isbf16; };
struct CArgs { CDesc d[16]; unsigned total; };

__global__ __launch_bounds__(256)
void multi_copy(CArgs ca)
{
    const unsigned idx = blockIdx.x * 256 + threadIdx.x;
    if (idx >= ca.total) return;
    int i = 0; unsigned start = 0;
    while (idx >= ca.d[i].end) { start = ca.d[i].end; ++i; }
    const CDesc cd = ca.d[i];
    const unsigned local = idx - start;
    const int r = local / cd.srcCols8;
    const int c = local % cd.srcCols8;
    u16 o[8];
    if (cd.isbf16) {
        *(uint4*)o = *(const uint4*)((const u16*)cd.src + ((size_t)r * cd.srcCols8 + c) * 8);
    } else {
        const float* s = (const float*)cd.src + ((size_t)r * cd.srcCols8 + c) * 8;
        const float4 a = *(const float4*)s;
        const float4 bq = *(const float4*)(s + 4);
        const float* ap = (const float*)&a;
        const float* bp = (const float*)&bq;
#pragma unroll
        for (int j = 0; j < 4; ++j) { o[j] = f2b(ap[j]); o[4 + j] = f2b(bp[j]); }
    }
    *(uint4*)(cd.dst + (size_t)r * cd.dstStride + cd.dstOff + (size_t)c * 8) = *(uint4*)o;
}

extern "C" void kernel_launch(void* const* d_in, const int* in_sizes, int n_in,
                              void* d_out, int out_size, void* d_ws, size_t ws_size,
                              hipStream_t stream)
{
    const float* s_prev = (const float*)d_in[0];
    const float* w_prev = (const float*)d_in[1];
    const float* p_prev = (const float*)d_in[2];
    const float* e_t    = (const float*)d_in[3];
    const float* c_t    = (const float*)d_in[4];
    const float* fw1    = (const float*)d_in[5];
    const float* fb1    = (const float*)d_in[6];
    const float* fln_g  = (const float*)d_in[7];
    const float* fln_b  = (const float*)d_in[8];
    const float* fw2    = (const float*)d_in[9];
    const float* fb2    = (const float*)d_in[10];
    const float* A_diag = (const float*)d_in[11];
    const float* A_U    = (const float*)d_in[12];
    const float* A_V    = (const float*)d_in[13];
    const float* amod_w = (const float*)d_in[14];
    const float* amod_b = (const float*)d_in[15];
    const float* bnet_w = (const float*)d_in[16];
    const float* bnet_b = (const float*)d_in[17];
    const float* pw1    = (const float*)d_in[18];
    const float* pb1    = (const float*)d_in[19];
    const float* pln_g  = (const float*)d_in[20];
    const float* pln_b  = (const float*)d_in[21];
    const float* pw2    = (const float*)d_in[22];
    const float* pb2    = (const float*)d_in[23];
    const float* pw3    = (const float*)d_in[24];
    const float* pb3    = (const float*)d_in[25];
    const float* gw     = (const float*)d_in[26];
    const float* gb     = (const float*)d_in[27];
    const float* uw     = (const float*)d_in[28];
    const float* up     = (const float*)d_in[29];
    const float* oln_g  = (const float*)d_in[30];
    const float* oln_b  = (const float*)d_in[31];

    float* out_s = (float*)d_out;
    float* out_w = out_s + (size_t)8192 * 1024;
    float* out_p = out_w + (size_t)8192 * 1024;

    u16* ws = (u16*)d_ws;
    u16* FIN  = ws;
    u16* W_bf = ws + 12582912;
    u16* H    = ws + 20971520;
    u16* P_bf = H;
    u16* Z    = ws + 29360128;
    u16* G    = ws + 33554432;
    u16* ACAT = ws + 41943040;
    u16* PM   = ACAT;
    u16* WM   = ACAT + 8388608;
    u16* WCAT = ws + 58720256;
    u16* wb   = ws + 60817408;
    u16* fw1b  = wb;
    u16* gwb   = wb + 2621440;
    u16* fw2b  = wb + 5242880;
    u16* amodb = wb + 5767168;
    u16* pw1b  = wb + 6291456;
    u16* pw2b  = wb + 7864320;
    u16* pw3b  = wb + 8388608;
    u16* uwb   = wb + 8650752;
    u16* upb   = wb + 9699328;
    u16* AUb   = wb + 10223616;
    u16* AVb   = wb + 10485760;

    const dim3 blk(256);
    const dim3 blk512(512);

    // ---------- batch 1
    {
        CArgs ca; unsigned cum = 0; int nd = 0;
        auto push = [&](const void* src, u16* dst, int cols8, int stride, int off,
                        int rows, int isbf) {
            cum += (unsigned)rows * cols8;
            ca.d[nd++] = CDesc{src, dst, cols8, stride, off, cum, isbf};
        };
        push(fw1,    fw1b,  320, 2560, 0,    1024, 0);
        push(gw,     gwb,   320, 2560, 0,    1024, 0);
        push(fw2,    fw2b,  128, 1024, 0,    512,  0);
        push(amod_w, amodb, 64,  512,  0,    1024, 0);
        push(pw1,    pw1b,  192, 1536, 0,    1024, 0);
        push(pw2,    pw2b,  128, 1024, 0,    512,  0);
        push(pw3,    pw3b,  64,  512,  0,    512,  0);
        push(uw,     uwb,   128, 1024, 0,    1024, 0);
        push(up,     upb,   64,  512,  0,    1024, 0);
        push(A_U,    AUb,   32,  256,  0,    1024, 0);
        push(A_V,    AVb,   32,  256,  0,    1024, 0);
        push(s_prev, FIN,   128, 2560, 0,    8192, 0);
        push(e_t,    FIN,   128, 2560, 1024, 8192, 0);
        push(c_t,    FIN,   64,  2560, 2048, 8192, 0);
        push(c_t,    ACAT,  64,  2048, 1024, 8192, 0);
        push(bnet_w, WCAT,  128, 2048, 1024, 1024, 0);
        ca.total = cum;
        multi_copy<<<dim3((cum + 255) / 256), blk, 0, stream>>>(ca);
    }

    // ---------- fused GEMM 1: fw1 (H) || gate (G) -> 256 blocks
    {
        GArgs ga;
        ga.d0 = GDesc{FIN, fw1b, fb1, nullptr, H, nullptr, 2560, 1024, 1024, 2560, EP_NONE,    32};
        ga.d1 = GDesc{FIN, gwb,  gb,  nullptr, G, nullptr, 2560, 1024, 1024, 2560, EP_SIGMOID, 32};
        ga.d2 = ga.d1; ga.s1 = 128; ga.s2 = 256;
        gemm_v4<<<dim3(256), blk512, 0, stream>>>(ga);
    }
    ln1024<true><<<8192, blk, 0, stream>>>(H, fln_g, fln_b);

    // ---------- fused GEMM 2: fw2 (Z) || amod (ACAT) || A_base (WCAT) -> 208 blocks
    {
        GArgs ga;
        ga.d0 = GDesc{H,          fw2b,  fb2,     nullptr, Z,    nullptr, 1024, 512,  512,  1024, EP_NONE,     32};
        ga.d1 = GDesc{FIN + 2048, amodb, amod_b,  w_prev,  ACAT, nullptr, 2560, 2048, 1024, 512,  EP_TANH_MUL, 32};
        ga.d2 = GDesc{AUb,        AVb,   nullptr, A_diag,  WCAT, nullptr, 256,  2048, 1024, 256,  EP_DIAG,     4};
        ga.s1 = 64; ga.s2 = 192;
        gemm_v4<<<dim3(208), blk512, 0, stream>>>(ga);
    }

    // ---------- batch 2
    {
        CArgs ca; unsigned cum = 0; int nd = 0;
        auto push = [&](const void* src, u16* dst, int cols8, int stride, int off,
                        int rows, int isbf) {
            cum += (unsigned)rows * cols8;
            ca.d[nd++] = CDesc{src, dst, cols8, stride, off, cum, isbf};
        };
        push(p_prev, FIN,  64, 1536, 0,    8192, 0);
        push(Z,      FIN,  64, 1536, 512,  8192, 1);
        push(c_t,    FIN,  64, 1536, 1024, 8192, 0);
        push(Z,      ACAT, 64, 2048, 1536, 8192, 1);
        ca.total = cum;
        multi_copy<<<dim3((cum + 255) / 256), blk, 0, stream>>>(ca);
    }

    // ---------- fused GEMM 3: w_t (ACAT@WCAT^T) || pw1 (PIN) -> 256 blocks
    {
        GArgs ga;
        ga.d0 = GDesc{ACAT, WCAT, bnet_b, nullptr, W_bf, out_w,   2048, 1024, 1024, 2048, EP_NONE, 32};
        ga.d1 = GDesc{FIN,  pw1b, pb1,    nullptr, H,    nullptr, 1536, 1024, 1024, 1536, EP_NONE, 32};
        ga.d2 = ga.d1; ga.s1 = 128; ga.s2 = 256;
        gemm_v4<<<dim3(256), blk512, 0, stream>>>(ga);
    }
    ln1024<true><<<8192, blk, 0, stream>>>(H, pln_g, pln_b);

    // ---------- fused GEMM 4: pw2 (H -> Z, relu) || uw (W_bf -> WM) -> 192 blocks
    {
        GArgs ga;
        ga.d0 = GDesc{H,    pw2b, pb2,     nullptr, Z,  nullptr, 1024, 512,  512,  1024, EP_RELU, 32};
        ga.d1 = GDesc{W_bf, uwb,  nullptr, nullptr, WM, nullptr, 1024, 1024, 1024, 1024, EP_NONE, 32};
        ga.d2 = ga.d1; ga.s1 = 64; ga.s2 = 192;
        gemm_v4<<<dim3(192), blk512, 0, stream>>>(ga);
    }

    // ---------- pw3
    {
        GArgs ga;
        ga.d0 = GDesc{Z, pw3b, pb3, p_prev, P_bf, out_p, 512, 512, 512, 512, EP_TANH_ADD, 32};
        ga.d1 = ga.d0; ga.d2 = ga.d0; ga.s1 = 64; ga.s2 = 64;
        gemm_v4<<<dim3(64), blk512, 0, stream>>>(ga);
    }

    // ---------- up
    {
        GArgs ga;
        ga.d0 = GDesc{P_bf, upb, nullptr, nullptr, PM, nullptr, 512, 1024, 1024, 512, EP_NONE, 32};
        ga.d1 = ga.d0; ga.d2 = ga.d0; ga.s1 = 128; ga.s2 = 128;
        gemm_v4<<<dim3(128), blk512, 0, stream>>>(ga);
    }

    mix_ln<<<8192, blk, 0, stream>>>(s_prev, G, PM, WM, oln_g, oln_b, out_s);
}

// Round 12
// 496.093 us; speedup vs baseline: 1.1097x; 1.0636x over previous
//
#include <hip/hip_runtime.h>
#include <math.h>

typedef unsigned short u16;
typedef __attribute__((ext_vector_type(8))) short short8;
typedef __attribute__((ext_vector_type(4))) float f32x4;

#define AS1C(p) ((const __attribute__((address_space(1))) void*)(p))
#define AS3(p)  ((__attribute__((address_space(3))) void*)(p))

static __device__ __forceinline__ float b2f(u16 h) {
    union { unsigned u; float f; } c; c.u = ((unsigned)h) << 16; return c.f;
}
static __device__ __forceinline__ u16 f2b(float f) {
    union { float f; unsigned u; } c; c.f = f;
    unsigned r = c.u + 0x7FFFu + ((c.u >> 16) & 1u);
    return (u16)(r >> 16);
}

// Epilogue modes (runtime)
#define EP_NONE     0
#define EP_RELU     1
#define EP_SIGMOID  2
#define EP_TANH_MUL 3
#define EP_TANH_ADD 4
#define EP_DIAG     5

struct GDesc {
    const u16* A;
    const u16* W;
    const float* bias;
    const float* auxf;
    u16* outb;
    float* outf;
    u16* outb2;         // optional second bf16 dest (col-offset copy) or null
    int lda, ldd, N, K, ep, nbm, ldd2, coff2;
};

struct GArgs { GDesc d0, d1, d2; int s1, s2; };

// ====================== gemm_v2: 256x256, 8 waves (R9 verbatim) ============
// 4-phase K-tile pipeline with read-ahead; counted vmcnt(4); staging order
// Ah0,Bh0,Bh1,Ah1; reads one phase ahead of their MFMA. Zero bank conflicts
// via both-sides swizzle. REQUIRES K%64==0 and nkt even.
__global__ __launch_bounds__(512, 2)
void gemm_v2(GArgs ga)
{
    __shared__ __align__(16) u16 LDS[65536];

    const int bid = (int)blockIdx.x;
    GDesc dd = (bid < ga.s1) ? ga.d0 : ((bid < ga.s2) ? ga.d1 : ga.d2);
    const int b = bid - ((bid < ga.s1) ? 0 : ((bid < ga.s2) ? ga.s1 : ga.s2));

    const int tid  = threadIdx.x;
    const int lane = tid & 63;
    const int wid  = tid >> 6;
    const int wr   = wid >> 2;          // 0..1
    const int wc   = wid & 3;           // 0..3

    const int bm = b % dd.nbm;
    const int bn = b / dd.nbm;
    const int lda = dd.lda, K = dd.K, N = dd.N, ldd = dd.ldd;
    const int nkt = K >> 6;

    const int srow  = tid >> 3;
    const int sslot = tid & 7;
    const int sgcol = (sslot ^ (srow & 7)) * 8;
    const u16* Ag = dd.A + (size_t)(bm * 256 + srow) * lda + sgcol;
    const u16* Wg = dd.W + (size_t)(bn * 256 + srow) * K + sgcol;
    const int ldst = tid * 8;

    f32x4 acc[8][4];
#pragma unroll
    for (int m = 0; m < 8; ++m)
#pragma unroll
        for (int n = 0; n < 4; ++n) acc[m][n] = (f32x4){0.f, 0.f, 0.f, 0.f};

    const int swz  = (lane & 7) << 4;
    const int cnat = (lane >> 4) << 4;
    const int aRow = (wr * 64 + (lane & 15)) * 64;
    const int bRow = (wc * 32 + (lane & 15)) * 64;
    const u16* pA00 = LDS + aRow + ((cnat ^ swz) >> 1);
    const u16* pA10 = LDS + aRow + ((((64) | cnat) ^ swz) >> 1);
    const u16* pA01 = pA00 + 32768;
    const u16* pA11 = pA10 + 32768;
    const u16* pB00 = LDS + 16384 + bRow + ((cnat ^ swz) >> 1);
    const u16* pB10 = LDS + 16384 + bRow + ((((64) | cnat) ^ swz) >> 1);
    const u16* pB01 = pB00 + 32768;
    const u16* pB11 = pB10 + 32768;

    short8 A0f[4][2], A1f[4][2], B0f[2][2], B1f[2][2];

#define READ_A(AF, PK0, PK1, MHOFF)                                              \
    {                                                                            \
        _Pragma("unroll")                                                        \
        for (int mm = 0; mm < 4; ++mm) {                                         \
            AF[mm][0] = *(const short8*)((PK0) + (MHOFF) + mm * 1024);           \
            AF[mm][1] = *(const short8*)((PK1) + (MHOFF) + mm * 1024);           \
        }                                                                        \
    }
#define READ_B(BF, PK0, PK1, NHOFF)                                              \
    {                                                                            \
        _Pragma("unroll")                                                        \
        for (int nn = 0; nn < 2; ++nn) {                                         \
            BF[nn][0] = *(const short8*)((PK0) + (NHOFF) + nn * 1024);           \
            BF[nn][1] = *(const short8*)((PK1) + (NHOFF) + nn * 1024);           \
        }                                                                        \
    }

#define STAGE_A(bufi, k0_, h)                                                    \
    {                                                                            \
        u16* d_ = &LDS[(bufi) * 32768 + ldst];                                   \
        _Pragma("unroll")                                                        \
        for (int j = 2 * (h); j < 2 * (h) + 2; ++j)                              \
            __builtin_amdgcn_global_load_lds(AS1C(Ag + (size_t)(j * 64) * lda + (k0_)), \
                                             AS3(d_ + j * 4096), 16, 0, 0);      \
    }
#define STAGE_B(bufi, k0_, h)                                                    \
    {                                                                            \
        u16* d_ = &LDS[(bufi) * 32768 + 16384 + ldst];                           \
        _Pragma("unroll")                                                        \
        for (int j = 2 * (h); j < 2 * (h) + 2; ++j)                              \
            __builtin_amdgcn_global_load_lds(AS1C(Wg + (size_t)(j * 64) * K + (k0_)),   \
                                             AS3(d_ + j * 4096), 16, 0, 0);      \
    }

#define VW4()                                                                    \
    {                                                                            \
        __builtin_amdgcn_sched_barrier(0);                                       \
        asm volatile("s_waitcnt vmcnt(4)" ::: "memory");                         \
        __builtin_amdgcn_sched_barrier(0);                                       \
        __builtin_amdgcn_s_barrier();                                            \
        __builtin_amdgcn_sched_barrier(0);                                       \
    }

#define QMFMA(AF, BF, mh, nh)                                                    \
    {                                                                            \
        __builtin_amdgcn_s_setprio(1);                                           \
        _Pragma("unroll")                                                        \
        for (int mm = 0; mm < 4; ++mm)                                           \
            _Pragma("unroll")                                                    \
            for (int nn = 0; nn < 2; ++nn)                                       \
                _Pragma("unroll")                                                \
                for (int ks = 0; ks < 2; ++ks)                                   \
                    acc[(mh) * 4 + mm][(nh) * 2 + nn] =                          \
                        __builtin_amdgcn_mfma_f32_16x16x32_bf16(                 \
                            AF[mm][ks], BF[nn][ks], acc[(mh) * 4 + mm][(nh) * 2 + nn], 0, 0, 0); \
        __builtin_amdgcn_s_setprio(0);                                           \
    }

#define TILE(NBUF, CA0, CA1, CBp0, CBp1, NA0, NA1, NBp0, NBp1, ktv)              \
    {                                                                            \
        const int ka_ = ((ktv) + 1 < nkt) ? (ktv) + 1 : nkt - 1;                 \
        const int k0n = ka_ << 6;                                                \
        STAGE_A(NBUF, k0n, 0);                                                   \
        VW4();                                                                   \
        QMFMA(A0f, B0f, 0, 0);                                                   \
        READ_B(B1f, CBp0, CBp1, 8192);                                           \
        STAGE_B(NBUF, k0n, 0);                                                   \
        VW4();                                                                   \
        QMFMA(A0f, B1f, 0, 1);                                                   \
        READ_A(A1f, CA0, CA1, 8192);                                             \
        STAGE_B(NBUF, k0n, 1);                                                   \
        VW4();                                                                   \
        QMFMA(A1f, B1f, 1, 1);                                                   \
        READ_A(A0f, NA0, NA1, 0);                                                \
        STAGE_A(NBUF, k0n, 1);                                                   \
        VW4();                                                                   \
        QMFMA(A1f, B0f, 1, 0);                                                   \
        READ_B(B0f, NBp0, NBp1, 0);                                              \
    }

    STAGE_A(0, 0, 0);
    __builtin_amdgcn_sched_barrier(0);
    STAGE_B(0, 0, 0);
    __builtin_amdgcn_sched_barrier(0);
    STAGE_B(0, 0, 1);
    __builtin_amdgcn_sched_barrier(0);
    STAGE_A(0, 0, 1);
    __builtin_amdgcn_sched_barrier(0);
    asm volatile("s_waitcnt vmcnt(4)" ::: "memory");
    __builtin_amdgcn_sched_barrier(0);
    __builtin_amdgcn_s_barrier();
    __builtin_amdgcn_sched_barrier(0);
    READ_A(A0f, pA00, pA10, 0);
    READ_B(B0f, pB00, pB10, 0);

    for (int kt = 0; kt < nkt; kt += 2) {
        TILE(1, pA00, pA10, pB00, pB10, pA01, pA11, pB01, pB11, kt);
        TILE(0, pA01, pA11, pB01, pB11, pA00, pA10, pB00, pB10, kt + 1);
    }

#undef READ_A
#undef READ_B
#undef STAGE_A
#undef STAGE_B
#undef VW4
#undef QMFMA
#undef TILE

    const int ep = dd.ep;
#pragma unroll
    for (int n = 0; n < 4; ++n) {
        const int C = bn * 256 + (n >> 1) * 128 + wc * 32 + (n & 1) * 16 + (lane & 15);
        const float bv = dd.bias ? dd.bias[C] : 0.f;
#pragma unroll
        for (int m = 0; m < 8; ++m) {
            const int R0 = bm * 256 + (m >> 2) * 128 + wr * 64 + (m & 3) * 16 + ((lane >> 4) << 2);
#pragma unroll
            for (int j = 0; j < 4; ++j) {
                const int R = R0 + j;
                float v = acc[m][n][j] + bv;
                if (ep == EP_RELU)          v = fmaxf(v, 0.f);
                else if (ep == EP_SIGMOID)  v = 1.f / (1.f + expf(-v));
                else if (ep == EP_TANH_MUL) v = tanhf(v) * dd.auxf[(size_t)R * N + C];
                else if (ep == EP_TANH_ADD) v = dd.auxf[(size_t)R * N + C] + tanhf(v);
                else if (ep == EP_DIAG)     { if (R == C) v += 0.9f * tanhf(dd.auxf[R]); }
                dd.outb[(size_t)R * ldd + C] = f2b(v);
                if (dd.outf) dd.outf[(size_t)R * N + C] = v;
            }
        }
    }
}

// ====================== gemm_s: 128x128, 4 waves, m97-structure =============
// Single-buffered 32 KB LDS (5 blocks/CU -> inter-block stall overlap, m114),
// 2 __syncthreads per K-tile, both-sides swizzle (zero bank conflicts).
// Mapping identical to R2's proven gemm_bt. Any K%64==0. Optional dual bf16
// output (outb2 at col offset coff2, stride ldd2).
__global__ __launch_bounds__(256)
void gemm_s(GArgs ga)
{
    __shared__ __align__(16) u16 As[8192];
    __shared__ __align__(16) u16 Bs[8192];

    const int bid = (int)blockIdx.x;
    GDesc dd = (bid < ga.s1) ? ga.d0 : ((bid < ga.s2) ? ga.d1 : ga.d2);
    const int b = bid - ((bid < ga.s1) ? 0 : ((bid < ga.s2) ? ga.s1 : ga.s2));

    const int tid  = threadIdx.x;
    const int lane = tid & 63;
    const int wave = tid >> 6;
    const int wr   = wave >> 1;
    const int wc   = wave & 1;

    const int bm = b % dd.nbm;
    const int bn = b / dd.nbm;
    const int lda = dd.lda, K = dd.K, N = dd.N, ldd = dd.ldd;

    // staging: rows srow + 32i (i=0..3), pre-swizzled source col
    const int srow  = tid >> 3;              // 0..31
    const int sslot = tid & 7;
    const int sgcol = (sslot ^ (srow & 7)) * 8;
    const u16* Ab = dd.A + (size_t)(bm * 128 + srow) * lda + sgcol;
    const u16* Wb = dd.W + (size_t)(bn * 128 + srow) * K + sgcol;
    u16* Asl = As + srow * 64 + sslot * 8;   // linear dest
    u16* Bsl = Bs + srow * 64 + sslot * 8;

    f32x4 acc[4][4];
#pragma unroll
    for (int m = 0; m < 4; ++m)
#pragma unroll
        for (int n = 0; n < 4; ++n) acc[m][n] = (f32x4){0.f, 0.f, 0.f, 0.f};

    // swizzled read pointers: row = (wr|wc)*64 + (lane&15) + m*16; byte col =
    // ((ks<<6)|cnat) ^ swz  (row&7 == lane&7)
    const int swz  = (lane & 7) << 4;
    const int cnat = (lane >> 4) << 4;
    const u16* pa0 = As + ((wr * 64) + (lane & 15)) * 64 + ((cnat ^ swz) >> 1);
    const u16* pa1 = As + ((wr * 64) + (lane & 15)) * 64 + ((((64) | cnat) ^ swz) >> 1);
    const u16* pb0 = Bs + ((wc * 64) + (lane & 15)) * 64 + ((cnat ^ swz) >> 1);
    const u16* pb1 = Bs + ((wc * 64) + (lane & 15)) * 64 + ((((64) | cnat) ^ swz) >> 1);

    for (int k0 = 0; k0 < K; k0 += 64) {
#pragma unroll
        for (int i = 0; i < 4; ++i) {
            __builtin_amdgcn_global_load_lds(AS1C(Ab + (size_t)(i * 32) * lda + k0),
                                             AS3(Asl + i * 32 * 64), 16, 0, 0);
            __builtin_amdgcn_global_load_lds(AS1C(Wb + (size_t)(i * 32) * K + k0),
                                             AS3(Bsl + i * 32 * 64), 16, 0, 0);
        }
        __syncthreads();
        short8 a[4][2], bb[4][2];
#pragma unroll
        for (int m = 0; m < 4; ++m) {
            a[m][0] = *(const short8*)(pa0 + m * 1024);
            a[m][1] = *(const short8*)(pa1 + m * 1024);
        }
#pragma unroll
        for (int n = 0; n < 4; ++n) {
            bb[n][0] = *(const short8*)(pb0 + n * 1024);
            bb[n][1] = *(const short8*)(pb1 + n * 1024);
        }
#pragma unroll
        for (int m = 0; m < 4; ++m)
#pragma unroll
            for (int n = 0; n < 4; ++n)
#pragma unroll
                for (int ks = 0; ks < 2; ++ks)
                    acc[m][n] = __builtin_amdgcn_mfma_f32_16x16x32_bf16(
                        a[m][ks], bb[n][ks], acc[m][n], 0, 0, 0);
        __syncthreads();
    }

    // epilogue (R2-proven): R = bm*128+wr*64+m*16+(lane>>4)*4+j, C = bn*128+wc*64+n*16+(lane&15)
    const int rbase = bm * 128 + wr * 64 + ((lane >> 4) << 2);
    const int cbase = bn * 128 + wc * 64 + (lane & 15);
    const int ep = dd.ep;
#pragma unroll
    for (int n = 0; n < 4; ++n) {
        const int C = cbase + n * 16;
        const float bv = dd.bias ? dd.bias[C] : 0.f;
#pragma unroll
        for (int m = 0; m < 4; ++m) {
            const int R0 = rbase + m * 16;
#pragma unroll
            for (int j = 0; j < 4; ++j) {
                const int R = R0 + j;
                float v = acc[m][n][j] + bv;
                if (ep == EP_RELU)          v = fmaxf(v, 0.f);
                else if (ep == EP_SIGMOID)  v = 1.f / (1.f + expf(-v));
                else if (ep == EP_TANH_MUL) v = tanhf(v) * dd.auxf[(size_t)R * N + C];
                else if (ep == EP_TANH_ADD) v = dd.auxf[(size_t)R * N + C] + tanhf(v);
                else if (ep == EP_DIAG)     { if (R == C) v += 0.9f * tanhf(dd.auxf[R]); }
                const u16 hb = f2b(v);
                dd.outb[(size_t)R * ldd + C] = hb;
                if (dd.outf)  dd.outf[(size_t)R * N + C] = v;
                if (dd.outb2) dd.outb2[(size_t)R * dd.ldd2 + C + dd.coff2] = hb;
            }
        }
    }
}

// In-place LayerNorm over D=1024 bf16 (+optional ReLU). gam/bet fp32.
template<bool RELU>
__global__ __launch_bounds__(256)
void ln1024(u16* __restrict__ X, const float* __restrict__ gam, const float* __restrict__ bet)
{
    const int row = blockIdx.x;
    u16* xp = X + (size_t)row * 1024 + threadIdx.x * 4;
    u16 loc[4];
    *(uint2*)loc = *(const uint2*)xp;
    float x0 = b2f(loc[0]), x1 = b2f(loc[1]), x2 = b2f(loc[2]), x3 = b2f(loc[3]);
    float s = x0 + x1 + x2 + x3;
    float q = x0 * x0 + x1 * x1 + x2 * x2 + x3 * x3;
#pragma unroll
    for (int off = 32; off; off >>= 1) { s += __shfl_xor(s, off); q += __shfl_xor(q, off); }
    __shared__ float sm[8];
    const int wave = threadIdx.x >> 6, lane = threadIdx.x & 63;
    if (lane == 0) { sm[wave] = s; sm[4 + wave] = q; }
    __syncthreads();
    s = sm[0] + sm[1] + sm[2] + sm[3];
    q = sm[4] + sm[5] + sm[6] + sm[7];
    const float mean = s * (1.f / 1024.f);
    const float var  = q * (1.f / 1024.f) - mean * mean;
    const float inv  = rsqrtf(var + 1e-5f);
    const int cb = threadIdx.x * 4;
#pragma unroll
    for (int j = 0; j < 4; ++j) {
        float y = (b2f(loc[j]) - mean) * inv * gam[cb + j] + bet[cb + j];
        if (RELU) y = fmaxf(y, 0.f);
        loc[j] = f2b(y);
    }
    *(uint2*)xp = *(uint2*)loc;
}

// s_t = LN(s_prev + g*pm + (1-g)*wm) over D=1024. sp fp32, g/pm/wm bf16, out fp32.
__global__ __launch_bounds__(256)
void mix_ln(const float* __restrict__ sp, const u16* __restrict__ gt,
            const u16* __restrict__ pm, const u16* __restrict__ wm,
            const float* __restrict__ og, const float* __restrict__ ob,
            float* __restrict__ out)
{
    const int row = blockIdx.x;
    const size_t base = (size_t)row * 1024 + threadIdx.x * 4;
    float4 lsp = *(const float4*)(sp + base);
    u16 lg[4], lp[4], lw[4];
    *(uint2*)lg = *(const uint2*)(gt + base);
    *(uint2*)lp = *(const uint2*)(pm + base);
    *(uint2*)lw = *(const uint2*)(wm + base);
    float x[4];
    const float* lspp = (const float*)&lsp;
#pragma unroll
    for (int j = 0; j < 4; ++j) {
        float g = b2f(lg[j]);
        x[j] = lspp[j] + g * b2f(lp[j]) + (1.f - g) * b2f(lw[j]);
    }
    float s = x[0] + x[1] + x[2] + x[3];
    float q = x[0]*x[0] + x[1]*x[1] + x[2]*x[2] + x[3]*x[3];
#pragma unroll
    for (int off = 32; off; off >>= 1) { s += __shfl_xor(s, off); q += __shfl_xor(q, off); }
    __shared__ float sm[8];
    const int wave = threadIdx.x >> 6, lane = threadIdx.x & 63;
    if (lane == 0) { sm[wave] = s; sm[4 + wave] = q; }
    __syncthreads();
    s = sm[0] + sm[1] + sm[2] + sm[3];
    q = sm[4] + sm[5] + sm[6] + sm[7];
    const float mean = s * (1.f / 1024.f);
    const float var  = q * (1.f / 1024.f) - mean * mean;
    const float inv  = rsqrtf(var + 1e-5f);
    const int cb = threadIdx.x * 4;
    float4 o;
    float* op = (float*)&o;
#pragma unroll
    for (int j = 0; j < 4; ++j)
        op[j] = (x[j] - mean) * inv * og[cb + j] + ob[cb + j];
    *(float4*)(out + base) = o;
}

// Batched strided copy/convert: fp32->bf16 or bf16->bf16, 8 elems/thread.
struct CDesc { const void* src; u16* dst; int srcCols8; int dstStride; int dstOff; unsigned end; int isbf16; };
struct CArgs { CDesc d[16]; unsigned total; };

__global__ __launch_bounds__(256)
void multi_copy(CArgs ca)
{
    const unsigned idx = blockIdx.x * 256 + threadIdx.x;
    if (idx >= ca.total) return;
    int i = 0; unsigned start = 0;
    while (idx >= ca.d[i].end) { start = ca.d[i].end; ++i; }
    const CDesc cd = ca.d[i];
    const unsigned local = idx - start;
    const int r = local / cd.srcCols8;
    const int c = local % cd.srcCols8;
    u16 o[8];
    if (cd.isbf16) {
        *(uint4*)o = *(const uint4*)((const u16*)cd.src + ((size_t)r * cd.srcCols8 + c) * 8);
    } else {
        const float* s = (const float*)cd.src + ((size_t)r * cd.srcCols8 + c) * 8;
        const float4 a = *(const float4*)s;
        const float4 bq = *(const float4*)(s + 4);
        const float* ap = (const float*)&a;
        const float* bp = (const float*)&bq;
#pragma unroll
        for (int j = 0; j < 4; ++j) { o[j] = f2b(ap[j]); o[4 + j] = f2b(bp[j]); }
    }
    *(uint4*)(cd.dst + (size_t)r * cd.dstStride + cd.dstOff + (size_t)c * 8) = *(uint4*)o;
}

extern "C" void kernel_launch(void* const* d_in, const int* in_sizes, int n_in,
                              void* d_out, int out_size, void* d_ws, size_t ws_size,
                              hipStream_t stream)
{
    const float* s_prev = (const float*)d_in[0];
    const float* w_prev = (const float*)d_in[1];
    const float* p_prev = (const float*)d_in[2];
    const float* e_t    = (const float*)d_in[3];
    const float* c_t    = (const float*)d_in[4];
    const float* fw1    = (const float*)d_in[5];
    const float* fb1    = (const float*)d_in[6];
    const float* fln_g  = (const float*)d_in[7];
    const float* fln_b  = (const float*)d_in[8];
    const float* fw2    = (const float*)d_in[9];
    const float* fb2    = (const float*)d_in[10];
    const float* A_diag = (const float*)d_in[11];
    const float* A_U    = (const float*)d_in[12];
    const float* A_V    = (const float*)d_in[13];
    const float* amod_w = (const float*)d_in[14];
    const float* amod_b = (const float*)d_in[15];
    const float* bnet_w = (const float*)d_in[16];
    const float* bnet_b = (const float*)d_in[17];
    const float* pw1    = (const float*)d_in[18];
    const float* pb1    = (const float*)d_in[19];
    const float* pln_g  = (const float*)d_in[20];
    const float* pln_b  = (const float*)d_in[21];
    const float* pw2    = (const float*)d_in[22];
    const float* pb2    = (const float*)d_in[23];
    const float* pw3    = (const float*)d_in[24];
    const float* pb3    = (const float*)d_in[25];
    const float* gw     = (const float*)d_in[26];
    const float* gb     = (const float*)d_in[27];
    const float* uw     = (const float*)d_in[28];
    const float* up     = (const float*)d_in[29];
    const float* oln_g  = (const float*)d_in[30];
    const float* oln_b  = (const float*)d_in[31];

    float* out_s = (float*)d_out;
    float* out_w = out_s + (size_t)8192 * 1024;
    float* out_p = out_w + (size_t)8192 * 1024;

    u16* ws = (u16*)d_ws;
    u16* FIN  = ws;
    u16* W_bf = ws + 12582912;
    u16* H    = ws + 20971520;
    u16* P_bf = H;
    u16* Z    = ws + 29360128;
    u16* G    = ws + 33554432;
    u16* ACAT = ws + 41943040;
    u16* PM   = ACAT;
    u16* WM   = ACAT + 8388608;
    u16* WCAT = ws + 58720256;
    u16* wb   = ws + 60817408;
    u16* fw1b  = wb;
    u16* gwb   = wb + 2621440;
    u16* fw2b  = wb + 5242880;
    u16* amodb = wb + 5767168;
    u16* pw1b  = wb + 6291456;
    u16* pw2b  = wb + 7864320;
    u16* pw3b  = wb + 8388608;
    u16* uwb   = wb + 8650752;
    u16* upb   = wb + 9699328;
    u16* AUb   = wb + 10223616;
    u16* AVb   = wb + 10485760;

    const dim3 blk(256);
    const dim3 blk512(512);

    // ---------- batch 1
    {
        CArgs ca; unsigned cum = 0; int nd = 0;
        auto push = [&](const void* src, u16* dst, int cols8, int stride, int off,
                        int rows, int isbf) {
            cum += (unsigned)rows * cols8;
            ca.d[nd++] = CDesc{src, dst, cols8, stride, off, cum, isbf};
        };
        push(fw1,    fw1b,  320, 2560, 0,    1024, 0);
        push(gw,     gwb,   320, 2560, 0,    1024, 0);
        push(fw2,    fw2b,  128, 1024, 0,    512,  0);
        push(amod_w, amodb, 64,  512,  0,    1024, 0);
        push(pw1,    pw1b,  192, 1536, 0,    1024, 0);
        push(pw2,    pw2b,  128, 1024, 0,    512,  0);
        push(pw3,    pw3b,  64,  512,  0,    512,  0);
        push(uw,     uwb,   128, 1024, 0,    1024, 0);
        push(up,     upb,   64,  512,  0,    1024, 0);
        push(A_U,    AUb,   32,  256,  0,    1024, 0);
        push(A_V,    AVb,   32,  256,  0,    1024, 0);
        push(s_prev, FIN,   128, 2560, 0,    8192, 0);
        push(e_t,    FIN,   128, 2560, 1024, 8192, 0);
        push(c_t,    FIN,   64,  2560, 2048, 8192, 0);
        push(c_t,    ACAT,  64,  2048, 1024, 8192, 0);
        push(bnet_w, WCAT,  128, 2048, 1024, 1024, 0);
        ca.total = cum;
        multi_copy<<<dim3((cum + 255) / 256), blk, 0, stream>>>(ca);
    }

    // ---------- fused GEMM 1 (256²): fw1 (H) || gate (G) -> 256 blocks
    {
        GArgs ga;
        ga.d0 = GDesc{FIN, fw1b, fb1, nullptr, H, nullptr, nullptr, 2560, 1024, 1024, 2560, EP_NONE,    32, 0, 0};
        ga.d1 = GDesc{FIN, gwb,  gb,  nullptr, G, nullptr, nullptr, 2560, 1024, 1024, 2560, EP_SIGMOID, 32, 0, 0};
        ga.d2 = ga.d1; ga.s1 = 128; ga.s2 = 256;
        gemm_v2<<<dim3(256), blk512, 0, stream>>>(ga);
    }
    ln1024<true><<<8192, blk, 0, stream>>>(H, fln_g, fln_b);

    // ---------- fused GEMM 2 (128²): fw2 (Z + ACAT col1536) || amod (ACAT) || A_base (WCAT)
    // 256 + 512 + 64 = 832 blocks
    {
        GArgs ga;
        ga.d0 = GDesc{H,          fw2b,  fb2,     nullptr, Z,    nullptr, ACAT,    1024, 512,  512,  1024, EP_NONE,     64, 2048, 1536};
        ga.d1 = GDesc{FIN + 2048, amodb, amod_b,  w_prev,  ACAT, nullptr, nullptr, 2560, 2048, 1024, 512,  EP_TANH_MUL, 64, 0, 0};
        ga.d2 = GDesc{AUb,        AVb,   nullptr, A_diag,  WCAT, nullptr, nullptr, 256,  2048, 1024, 256,  EP_DIAG,     8, 0, 0};
        ga.s1 = 256; ga.s2 = 768;
        gemm_s<<<dim3(832), blk, 0, stream>>>(ga);
    }

    // ---------- batch 2: PIN = [p_prev || z || c_t] at FIN base
    {
        CArgs ca; unsigned cum = 0; int nd = 0;
        auto push = [&](const void* src, u16* dst, int cols8, int stride, int off,
                        int rows, int isbf) {
            cum += (unsigned)rows * cols8;
            ca.d[nd++] = CDesc{src, dst, cols8, stride, off, cum, isbf};
        };
        push(p_prev, FIN,  64, 1536, 0,    8192, 0);
        push(Z,      FIN,  64, 1536, 512,  8192, 1);
        push(c_t,    FIN,  64, 1536, 1024, 8192, 0);
        ca.total = cum;
        multi_copy<<<dim3((cum + 255) / 256), blk, 0, stream>>>(ca);
    }

    // ---------- fused GEMM 3 (256²): w_t (ACAT@WCAT^T) || pw1 (PIN) -> 256 blocks
    {
        GArgs ga;
        ga.d0 = GDesc{ACAT, WCAT, bnet_b, nullptr, W_bf, out_w,   nullptr, 2048, 1024, 1024, 2048, EP_NONE, 32, 0, 0};
        ga.d1 = GDesc{FIN,  pw1b, pb1,    nullptr, H,    nullptr, nullptr, 1536, 1024, 1024, 1536, EP_NONE, 32, 0, 0};
        ga.d2 = ga.d1; ga.s1 = 128; ga.s2 = 256;
        gemm_v2<<<dim3(256), blk512, 0, stream>>>(ga);
    }
    ln1024<true><<<8192, blk, 0, stream>>>(H, pln_g, pln_b);

    // ---------- fused GEMM 4 (256²): pw2 (H -> Z, relu) || uw (W_bf -> WM) -> 192 blocks
    {
        GArgs ga;
        ga.d0 = GDesc{H,    pw2b, pb2,     nullptr, Z,  nullptr, nullptr, 1024, 512,  512,  1024, EP_RELU, 32, 0, 0};
        ga.d1 = GDesc{W_bf, uwb,  nullptr, nullptr, WM, nullptr, nullptr, 1024, 1024, 1024, 1024, EP_NONE, 32, 0, 0};
        ga.d2 = ga.d1; ga.s1 = 64; ga.s2 = 192;
        gemm_v2<<<dim3(192), blk512, 0, stream>>>(ga);
    }

    // ---------- pw3 (128²): p_t = p_prev + tanh(Z@pw3^T + pb3) -> 256 blocks
    {
        GArgs ga;
        ga.d0 = GDesc{Z, pw3b, pb3, p_prev, P_bf, out_p, nullptr, 512, 512, 512, 512, EP_TANH_ADD, 64, 0, 0};
        ga.d1 = ga.d0; ga.d2 = ga.d0; ga.s1 = 256; ga.s2 = 256;
        gemm_s<<<dim3(256), blk, 0, stream>>>(ga);
    }

    // ---------- up (128²): pm = P_bf @ up^T -> 512 blocks
    {
        GArgs ga;
        ga.d0 = GDesc{P_bf, upb, nullptr, nullptr, PM, nullptr, nullptr, 512, 1024, 1024, 512, EP_NONE, 64, 0, 0};
        ga.d1 = ga.d0; ga.d2 = ga.d0; ga.s1 = 512; ga.s2 = 512;
        gemm_s<<<dim3(512), blk, 0, stream>>>(ga);
    }

    mix_ln<<<8192, blk, 0, stream>>>(s_prev, G, PM, WM, oln_g, oln_b, out_s);
}

// Round 13
// 494.673 us; speedup vs baseline: 1.1129x; 1.0029x over previous
//
#include <hip/hip_runtime.h>
#include <math.h>

typedef unsigned short u16;
typedef __attribute__((ext_vector_type(8))) short short8;
typedef __attribute__((ext_vector_type(4))) float f32x4;

#define AS1C(p) ((const __attribute__((address_space(1))) void*)(p))
#define AS3(p)  ((__attribute__((address_space(3))) void*)(p))

static __device__ __forceinline__ float b2f(u16 h) {
    union { unsigned u; float f; } c; c.u = ((unsigned)h) << 16; return c.f;
}
static __device__ __forceinline__ u16 f2b(float f) {
    union { float f; unsigned u; } c; c.f = f;
    unsigned r = c.u + 0x7FFFu + ((c.u >> 16) & 1u);
    return (u16)(r >> 16);
}

// Epilogue modes (runtime)
#define EP_NONE     0
#define EP_RELU     1
#define EP_SIGMOID  2
#define EP_TANH_MUL 3
#define EP_TANH_ADD 4
#define EP_DIAG     5

struct GDesc {
    const u16* A;
    const u16* W;
    const float* bias;
    const float* auxf;
    u16* outb;
    float* outf;
    u16* outb2;         // optional second bf16 dest (col-offset copy) or null
    int lda, ldd, N, K, ep, nbm, ldd2, coff2;
};

struct GArgs { GDesc d0, d1, d2; int s1, s2; };

// ====================== gemm_z: 256x256, 8 waves, scheme Z =================
// R9's read-ahead rotation with minimized waits: per K-tile t
//   ph1: stage {A0,B0}(t+1) [4 loads]; vmcnt(4); barrier; read B1f(t); MFMA q00
//   ph2: stage B1(t+1) [2];            barrier; read A1f(t); MFMA q01
//   ph3: stage A1(t+1) [2]; vmcnt(4);  barrier;              MFMA q11
//   ph4: (no stage/sync)               MFMA q10; read A0f,B0f(t+1)
// Ledger: ph1's vmcnt(4) confirms {B1(t),A1(t)} (staged t-1 ph2/ph3, 2-3-phase
// flight); ph3's confirms {A0,B0}(t+1) (staged ph1, 2-phase flight) which ph4
// reads. 2 vmcnt + 3 barriers per tile (R9: 4+4); every wait is cold.
// Region-overwrite hazards all >=1 barrier separated (checked per A0/A1/B0/B1
// x parity). LDS swizzle (16B slot ^= row&7) both sides; precomputed ds ptrs;
// K-loop unrolled x2 for static parity. REQUIRES K%64==0 and nkt even.
__global__ __launch_bounds__(512, 2)
void gemm_z(GArgs ga)
{
    __shared__ __align__(16) u16 LDS[65536];

    const int bid = (int)blockIdx.x;
    GDesc dd = (bid < ga.s1) ? ga.d0 : ((bid < ga.s2) ? ga.d1 : ga.d2);
    const int b = bid - ((bid < ga.s1) ? 0 : ((bid < ga.s2) ? ga.s1 : ga.s2));

    const int tid  = threadIdx.x;
    const int lane = tid & 63;
    const int wid  = tid >> 6;
    const int wr   = wid >> 2;          // 0..1
    const int wc   = wid & 3;           // 0..3

    const int bm = b % dd.nbm;
    const int bn = b / dd.nbm;
    const int lda = dd.lda, K = dd.K, N = dd.N, ldd = dd.ldd;
    const int nkt = K >> 6;

    const int srow  = tid >> 3;
    const int sslot = tid & 7;
    const int sgcol = (sslot ^ (srow & 7)) * 8;
    const u16* Ag = dd.A + (size_t)(bm * 256 + srow) * lda + sgcol;
    const u16* Wg = dd.W + (size_t)(bn * 256 + srow) * K + sgcol;
    const int ldst = tid * 8;

    f32x4 acc[8][4];
#pragma unroll
    for (int m = 0; m < 8; ++m)
#pragma unroll
        for (int n = 0; n < 4; ++n) acc[m][n] = (f32x4){0.f, 0.f, 0.f, 0.f};

    const int swz  = (lane & 7) << 4;
    const int cnat = (lane >> 4) << 4;
    const int aRow = (wr * 64 + (lane & 15)) * 64;
    const int bRow = (wc * 32 + (lane & 15)) * 64;
    const u16* pA00 = LDS + aRow + ((cnat ^ swz) >> 1);
    const u16* pA10 = LDS + aRow + ((((64) | cnat) ^ swz) >> 1);
    const u16* pA01 = pA00 + 32768;
    const u16* pA11 = pA10 + 32768;
    const u16* pB00 = LDS + 16384 + bRow + ((cnat ^ swz) >> 1);
    const u16* pB10 = LDS + 16384 + bRow + ((((64) | cnat) ^ swz) >> 1);
    const u16* pB01 = pB00 + 32768;
    const u16* pB11 = pB10 + 32768;

    short8 A0f[4][2], A1f[4][2], B0f[2][2], B1f[2][2];

#define READ_A(AF, PK0, PK1, MHOFF)                                              \
    {                                                                            \
        _Pragma("unroll")                                                        \
        for (int mm = 0; mm < 4; ++mm) {                                         \
            AF[mm][0] = *(const short8*)((PK0) + (MHOFF) + mm * 1024);           \
            AF[mm][1] = *(const short8*)((PK1) + (MHOFF) + mm * 1024);           \
        }                                                                        \
    }
#define READ_B(BF, PK0, PK1, NHOFF)                                              \
    {                                                                            \
        _Pragma("unroll")                                                        \
        for (int nn = 0; nn < 2; ++nn) {                                         \
            BF[nn][0] = *(const short8*)((PK0) + (NHOFF) + nn * 1024);           \
            BF[nn][1] = *(const short8*)((PK1) + (NHOFF) + nn * 1024);           \
        }                                                                        \
    }

#define STAGE_A(bufi, k0_, h)                                                    \
    {                                                                            \
        u16* d_ = &LDS[(bufi) * 32768 + ldst];                                   \
        _Pragma("unroll")                                                        \
        for (int j = 2 * (h); j < 2 * (h) + 2; ++j)                              \
            __builtin_amdgcn_global_load_lds(AS1C(Ag + (size_t)(j * 64) * lda + (k0_)), \
                                             AS3(d_ + j * 4096), 16, 0, 0);      \
    }
#define STAGE_B(bufi, k0_, h)                                                    \
    {                                                                            \
        u16* d_ = &LDS[(bufi) * 32768 + 16384 + ldst];                           \
        _Pragma("unroll")                                                        \
        for (int j = 2 * (h); j < 2 * (h) + 2; ++j)                              \
            __builtin_amdgcn_global_load_lds(AS1C(Wg + (size_t)(j * 64) * K + (k0_)),   \
                                             AS3(d_ + j * 4096), 16, 0, 0);      \
    }

#define VWAIT4B()                                                                \
    {                                                                            \
        __builtin_amdgcn_sched_barrier(0);                                       \
        asm volatile("s_waitcnt vmcnt(4)" ::: "memory");                         \
        __builtin_amdgcn_sched_barrier(0);                                       \
        __builtin_amdgcn_s_barrier();                                            \
        __builtin_amdgcn_sched_barrier(0);                                       \
    }
#define BARONLY()                                                                \
    {                                                                            \
        __builtin_amdgcn_sched_barrier(0);                                       \
        __builtin_amdgcn_s_barrier();                                            \
        __builtin_amdgcn_sched_barrier(0);                                       \
    }

#define QMFMA(AF, BF, mh, nh)                                                    \
    {                                                                            \
        __builtin_amdgcn_s_setprio(1);                                           \
        _Pragma("unroll")                                                        \
        for (int mm = 0; mm < 4; ++mm)                                           \
            _Pragma("unroll")                                                    \
            for (int nn = 0; nn < 2; ++nn)                                       \
                _Pragma("unroll")                                                \
                for (int ks = 0; ks < 2; ++ks)                                   \
                    acc[(mh) * 4 + mm][(nh) * 2 + nn] =                          \
                        __builtin_amdgcn_mfma_f32_16x16x32_bf16(                 \
                            AF[mm][ks], BF[nn][ks], acc[(mh) * 4 + mm][(nh) * 2 + nn], 0, 0, 0); \
        __builtin_amdgcn_s_setprio(0);                                           \
    }

    // TILE reading buffer ptrs C*, staging into NBUF (ptrs N* for ph4 reads)
#define TILE(NBUF, CA0, CA1, CBp0, CBp1, NA0, NA1, NBp0, NBp1, ktv)              \
    {                                                                            \
        const int ka_ = ((ktv) + 1 < nkt) ? (ktv) + 1 : nkt - 1;                 \
        const int k0n = ka_ << 6;                                                \
        /* ph1 */                                                                \
        STAGE_A(NBUF, k0n, 0);                                                   \
        STAGE_B(NBUF, k0n, 0);                                                   \
        VWAIT4B();                                                               \
        READ_B(B1f, CBp0, CBp1, 8192);                                           \
        QMFMA(A0f, B0f, 0, 0);                                                   \
        /* ph2 */                                                                \
        STAGE_B(NBUF, k0n, 1);                                                   \
        BARONLY();                                                               \
        READ_A(A1f, CA0, CA1, 8192);                                             \
        QMFMA(A0f, B1f, 0, 1);                                                   \
        /* ph3 */                                                                \
        STAGE_A(NBUF, k0n, 1);                                                   \
        VWAIT4B();                                                               \
        QMFMA(A1f, B1f, 1, 1);                                                   \
        /* ph4: no stage, no sync */                                             \
        QMFMA(A1f, B0f, 1, 0);                                                   \
        READ_A(A0f, NA0, NA1, 0);                                                \
        READ_B(B0f, NBp0, NBp1, 0);                                              \
    }

    // ---- prologue: stage A0,B0,B1,A1 of tile 0 (order matters for vmcnt)
    STAGE_A(0, 0, 0);
    __builtin_amdgcn_sched_barrier(0);
    STAGE_B(0, 0, 0);
    __builtin_amdgcn_sched_barrier(0);
    STAGE_B(0, 0, 1);
    __builtin_amdgcn_sched_barrier(0);
    STAGE_A(0, 0, 1);
    VWAIT4B();
    READ_A(A0f, pA00, pA10, 0);
    READ_B(B0f, pB00, pB10, 0);

    for (int kt = 0; kt < nkt; kt += 2) {
        TILE(1, pA00, pA10, pB00, pB10, pA01, pA11, pB01, pB11, kt);
        TILE(0, pA01, pA11, pB01, pB11, pA00, pA10, pB00, pB10, kt + 1);
    }

#undef READ_A
#undef READ_B
#undef STAGE_A
#undef STAGE_B
#undef VWAIT4B
#undef BARONLY
#undef QMFMA
#undef TILE

    const int ep = dd.ep;
#pragma unroll
    for (int n = 0; n < 4; ++n) {
        const int C = bn * 256 + (n >> 1) * 128 + wc * 32 + (n & 1) * 16 + (lane & 15);
        const float bv = dd.bias ? dd.bias[C] : 0.f;
#pragma unroll
        for (int m = 0; m < 8; ++m) {
            const int R0 = bm * 256 + (m >> 2) * 128 + wr * 64 + (m & 3) * 16 + ((lane >> 4) << 2);
#pragma unroll
            for (int j = 0; j < 4; ++j) {
                const int R = R0 + j;
                float v = acc[m][n][j] + bv;
                if (ep == EP_RELU)          v = fmaxf(v, 0.f);
                else if (ep == EP_SIGMOID)  v = 1.f / (1.f + expf(-v));
                else if (ep == EP_TANH_MUL) v = tanhf(v) * dd.auxf[(size_t)R * N + C];
                else if (ep == EP_TANH_ADD) v = dd.auxf[(size_t)R * N + C] + tanhf(v);
                else if (ep == EP_DIAG)     { if (R == C) v += 0.9f * tanhf(dd.auxf[R]); }
                dd.outb[(size_t)R * ldd + C] = f2b(v);
                if (dd.outf) dd.outf[(size_t)R * N + C] = v;
            }
        }
    }
}

// ====================== gemm_s: 128x128, 4 waves, m97-structure =============
__global__ __launch_bounds__(256)
void gemm_s(GArgs ga)
{
    __shared__ __align__(16) u16 As[8192];
    __shared__ __align__(16) u16 Bs[8192];

    const int bid = (int)blockIdx.x;
    GDesc dd = (bid < ga.s1) ? ga.d0 : ((bid < ga.s2) ? ga.d1 : ga.d2);
    const int b = bid - ((bid < ga.s1) ? 0 : ((bid < ga.s2) ? ga.s1 : ga.s2));

    const int tid  = threadIdx.x;
    const int lane = tid & 63;
    const int wave = tid >> 6;
    const int wr   = wave >> 1;
    const int wc   = wave & 1;

    const int bm = b % dd.nbm;
    const int bn = b / dd.nbm;
    const int lda = dd.lda, K = dd.K, N = dd.N, ldd = dd.ldd;

    const int srow  = tid >> 3;
    const int sslot = tid & 7;
    const int sgcol = (sslot ^ (srow & 7)) * 8;
    const u16* Ab = dd.A + (size_t)(bm * 128 + srow) * lda + sgcol;
    const u16* Wb = dd.W + (size_t)(bn * 128 + srow) * K + sgcol;
    u16* Asl = As + srow * 64 + sslot * 8;
    u16* Bsl = Bs + srow * 64 + sslot * 8;

    f32x4 acc[4][4];
#pragma unroll
    for (int m = 0; m < 4; ++m)
#pragma unroll
        for (int n = 0; n < 4; ++n) acc[m][n] = (f32x4){0.f, 0.f, 0.f, 0.f};

    const int swz  = (lane & 7) << 4;
    const int cnat = (lane >> 4) << 4;
    const u16* pa0 = As + ((wr * 64) + (lane & 15)) * 64 + ((cnat ^ swz) >> 1);
    const u16* pa1 = As + ((wr * 64) + (lane & 15)) * 64 + ((((64) | cnat) ^ swz) >> 1);
    const u16* pb0 = Bs + ((wc * 64) + (lane & 15)) * 64 + ((cnat ^ swz) >> 1);
    const u16* pb1 = Bs + ((wc * 64) + (lane & 15)) * 64 + ((((64) | cnat) ^ swz) >> 1);

    for (int k0 = 0; k0 < K; k0 += 64) {
#pragma unroll
        for (int i = 0; i < 4; ++i) {
            __builtin_amdgcn_global_load_lds(AS1C(Ab + (size_t)(i * 32) * lda + k0),
                                             AS3(Asl + i * 32 * 64), 16, 0, 0);
            __builtin_amdgcn_global_load_lds(AS1C(Wb + (size_t)(i * 32) * K + k0),
                                             AS3(Bsl + i * 32 * 64), 16, 0, 0);
        }
        __syncthreads();
        short8 a[4][2], bb[4][2];
#pragma unroll
        for (int m = 0; m < 4; ++m) {
            a[m][0] = *(const short8*)(pa0 + m * 1024);
            a[m][1] = *(const short8*)(pa1 + m * 1024);
        }
#pragma unroll
        for (int n = 0; n < 4; ++n) {
            bb[n][0] = *(const short8*)(pb0 + n * 1024);
            bb[n][1] = *(const short8*)(pb1 + n * 1024);
        }
#pragma unroll
        for (int m = 0; m < 4; ++m)
#pragma unroll
            for (int n = 0; n < 4; ++n)
#pragma unroll
                for (int ks = 0; ks < 2; ++ks)
                    acc[m][n] = __builtin_amdgcn_mfma_f32_16x16x32_bf16(
                        a[m][ks], bb[n][ks], acc[m][n], 0, 0, 0);
        __syncthreads();
    }

    const int rbase = bm * 128 + wr * 64 + ((lane >> 4) << 2);
    const int cbase = bn * 128 + wc * 64 + (lane & 15);
    const int ep = dd.ep;
#pragma unroll
    for (int n = 0; n < 4; ++n) {
        const int C = cbase + n * 16;
        const float bv = dd.bias ? dd.bias[C] : 0.f;
#pragma unroll
        for (int m = 0; m < 4; ++m) {
            const int R0 = rbase + m * 16;
#pragma unroll
            for (int j = 0; j < 4; ++j) {
                const int R = R0 + j;
                float v = acc[m][n][j] + bv;
                if (ep == EP_RELU)          v = fmaxf(v, 0.f);
                else if (ep == EP_SIGMOID)  v = 1.f / (1.f + expf(-v));
                else if (ep == EP_TANH_MUL) v = tanhf(v) * dd.auxf[(size_t)R * N + C];
                else if (ep == EP_TANH_ADD) v = dd.auxf[(size_t)R * N + C] + tanhf(v);
                else if (ep == EP_DIAG)     { if (R == C) v += 0.9f * tanhf(dd.auxf[R]); }
                const u16 hb = f2b(v);
                dd.outb[(size_t)R * ldd + C] = hb;
                if (dd.outf)  dd.outf[(size_t)R * N + C] = v;
                if (dd.outb2) dd.outb2[(size_t)R * dd.ldd2 + C + dd.coff2] = hb;
            }
        }
    }
}

// In-place LayerNorm over D=1024 bf16 (+optional ReLU). gam/bet fp32.
template<bool RELU>
__global__ __launch_bounds__(256)
void ln1024(u16* __restrict__ X, const float* __restrict__ gam, const float* __restrict__ bet)
{
    const int row = blockIdx.x;
    u16* xp = X + (size_t)row * 1024 + threadIdx.x * 4;
    u16 loc[4];
    *(uint2*)loc = *(const uint2*)xp;
    float x0 = b2f(loc[0]), x1 = b2f(loc[1]), x2 = b2f(loc[2]), x3 = b2f(loc[3]);
    float s = x0 + x1 + x2 + x3;
    float q = x0 * x0 + x1 * x1 + x2 * x2 + x3 * x3;
#pragma unroll
    for (int off = 32; off; off >>= 1) { s += __shfl_xor(s, off); q += __shfl_xor(q, off); }
    __shared__ float sm[8];
    const int wave = threadIdx.x >> 6, lane = threadIdx.x & 63;
    if (lane == 0) { sm[wave] = s; sm[4 + wave] = q; }
    __syncthreads();
    s = sm[0] + sm[1] + sm[2] + sm[3];
    q = sm[4] + sm[5] + sm[6] + sm[7];
    const float mean = s * (1.f / 1024.f);
    const float var  = q * (1.f / 1024.f) - mean * mean;
    const float inv  = rsqrtf(var + 1e-5f);
    const int cb = threadIdx.x * 4;
#pragma unroll
    for (int j = 0; j < 4; ++j) {
        float y = (b2f(loc[j]) - mean) * inv * gam[cb + j] + bet[cb + j];
        if (RELU) y = fmaxf(y, 0.f);
        loc[j] = f2b(y);
    }
    *(uint2*)xp = *(uint2*)loc;
}

// s_t = LN(s_prev + g*pm + (1-g)*wm) over D=1024. sp fp32, g/pm/wm bf16, out fp32.
__global__ __launch_bounds__(256)
void mix_ln(const float* __restrict__ sp, const u16* __restrict__ gt,
            const u16* __restrict__ pm, const u16* __restrict__ wm,
            const float* __restrict__ og, const float* __restrict__ ob,
            float* __restrict__ out)
{
    const int row = blockIdx.x;
    const size_t base = (size_t)row * 1024 + threadIdx.x * 4;
    float4 lsp = *(const float4*)(sp + base);
    u16 lg[4], lp[4], lw[4];
    *(uint2*)lg = *(const uint2*)(gt + base);
    *(uint2*)lp = *(const uint2*)(pm + base);
    *(uint2*)lw = *(const uint2*)(wm + base);
    float x[4];
    const float* lspp = (const float*)&lsp;
#pragma unroll
    for (int j = 0; j < 4; ++j) {
        float g = b2f(lg[j]);
        x[j] = lspp[j] + g * b2f(lp[j]) + (1.f - g) * b2f(lw[j]);
    }
    float s = x[0] + x[1] + x[2] + x[3];
    float q = x[0]*x[0] + x[1]*x[1] + x[2]*x[2] + x[3]*x[3];
#pragma unroll
    for (int off = 32; off; off >>= 1) { s += __shfl_xor(s, off); q += __shfl_xor(q, off); }
    __shared__ float sm[8];
    const int wave = threadIdx.x >> 6, lane = threadIdx.x & 63;
    if (lane == 0) { sm[wave] = s; sm[4 + wave] = q; }
    __syncthreads();
    s = sm[0] + sm[1] + sm[2] + sm[3];
    q = sm[4] + sm[5] + sm[6] + sm[7];
    const float mean = s * (1.f / 1024.f);
    const float var  = q * (1.f / 1024.f) - mean * mean;
    const float inv  = rsqrtf(var + 1e-5f);
    const int cb = threadIdx.x * 4;
    float4 o;
    float* op = (float*)&o;
#pragma unroll
    for (int j = 0; j < 4; ++j)
        op[j] = (x[j] - mean) * inv * og[cb + j] + ob[cb + j];
    *(float4*)(out + base) = o;
}

// Batched strided copy/convert: fp32->bf16 or bf16->bf16, 8 elems/thread.
struct CDesc { const void* src; u16* dst; int srcCols8; int dstStride; int dstOff; unsigned end; int isbf16; };
struct CArgs { CDesc d[16]; unsigned total; };

__global__ __launch_bounds__(256)
void multi_copy(CArgs ca)
{
    const unsigned idx = blockIdx.x * 256 + threadIdx.x;
    if (idx >= ca.total) return;
    int i = 0; unsigned start = 0;
    while (idx >= ca.d[i].end) { start = ca.d[i].end; ++i; }
    const CDesc cd = ca.d[i];
    const unsigned local = idx - start;
    const int r = local / cd.srcCols8;
    const int c = local % cd.srcCols8;
    u16 o[8];
    if (cd.isbf16) {
        *(uint4*)o = *(const uint4*)((const u16*)cd.src + ((size_t)r * cd.srcCols8 + c) * 8);
    } else {
        const float* s = (const float*)cd.src + ((size_t)r * cd.srcCols8 + c) * 8;
        const float4 a = *(const float4*)s;
        const float4 bq = *(const float4*)(s + 4);
        const float* ap = (const float*)&a;
        const float* bp = (const float*)&bq;
#pragma unroll
        for (int j = 0; j < 4; ++j) { o[j] = f2b(ap[j]); o[4 + j] = f2b(bp[j]); }
    }
    *(uint4*)(cd.dst + (size_t)r * cd.dstStride + cd.dstOff + (size_t)c * 8) = *(uint4*)o;
}

extern "C" void kernel_launch(void* const* d_in, const int* in_sizes, int n_in,
                              void* d_out, int out_size, void* d_ws, size_t ws_size,
                              hipStream_t stream)
{
    const float* s_prev = (const float*)d_in[0];
    const float* w_prev = (const float*)d_in[1];
    const float* p_prev = (const float*)d_in[2];
    const float* e_t    = (const float*)d_in[3];
    const float* c_t    = (const float*)d_in[4];
    const float* fw1    = (const float*)d_in[5];
    const float* fb1    = (const float*)d_in[6];
    const float* fln_g  = (const float*)d_in[7];
    const float* fln_b  = (const float*)d_in[8];
    const float* fw2    = (const float*)d_in[9];
    const float* fb2    = (const float*)d_in[10];
    const float* A_diag = (const float*)d_in[11];
    const float* A_U    = (const float*)d_in[12];
    const float* A_V    = (const float*)d_in[13];
    const float* amod_w = (const float*)d_in[14];
    const float* amod_b = (const float*)d_in[15];
    const float* bnet_w = (const float*)d_in[16];
    const float* bnet_b = (const float*)d_in[17];
    const float* pw1    = (const float*)d_in[18];
    const float* pb1    = (const float*)d_in[19];
    const float* pln_g  = (const float*)d_in[20];
    const float* pln_b  = (const float*)d_in[21];
    const float* pw2    = (const float*)d_in[22];
    const float* pb2    = (const float*)d_in[23];
    const float* pw3    = (const float*)d_in[24];
    const float* pb3    = (const float*)d_in[25];
    const float* gw     = (const float*)d_in[26];
    const float* gb     = (const float*)d_in[27];
    const float* uw     = (const float*)d_in[28];
    const float* up     = (const float*)d_in[29];
    const float* oln_g  = (const float*)d_in[30];
    const float* oln_b  = (const float*)d_in[31];

    float* out_s = (float*)d_out;
    float* out_w = out_s + (size_t)8192 * 1024;
    float* out_p = out_w + (size_t)8192 * 1024;

    u16* ws = (u16*)d_ws;
    u16* FIN  = ws;
    u16* W_bf = ws + 12582912;
    u16* H    = ws + 20971520;
    u16* P_bf = H;
    u16* Z    = ws + 29360128;
    u16* G    = ws + 33554432;
    u16* ACAT = ws + 41943040;
    u16* PM   = ACAT;
    u16* WM   = ACAT + 8388608;
    u16* WCAT = ws + 58720256;
    u16* wb   = ws + 60817408;
    u16* fw1b  = wb;
    u16* gwb   = wb + 2621440;
    u16* fw2b  = wb + 5242880;
    u16* amodb = wb + 5767168;
    u16* pw1b  = wb + 6291456;
    u16* pw2b  = wb + 7864320;
    u16* pw3b  = wb + 8388608;
    u16* uwb   = wb + 8650752;
    u16* upb   = wb + 9699328;
    u16* AUb   = wb + 10223616;
    u16* AVb   = wb + 10485760;

    const dim3 blk(256);
    const dim3 blk512(512);

    // ---------- batch 1
    {
        CArgs ca; unsigned cum = 0; int nd = 0;
        auto push = [&](const void* src, u16* dst, int cols8, int stride, int off,
                        int rows, int isbf) {
            cum += (unsigned)rows * cols8;
            ca.d[nd++] = CDesc{src, dst, cols8, stride, off, cum, isbf};
        };
        push(fw1,    fw1b,  320, 2560, 0,    1024, 0);
        push(gw,     gwb,   320, 2560, 0,    1024, 0);
        push(fw2,    fw2b,  128, 1024, 0,    512,  0);
        push(amod_w, amodb, 64,  512,  0,    1024, 0);
        push(pw1,    pw1b,  192, 1536, 0,    1024, 0);
        push(pw2,    pw2b,  128, 1024, 0,    512,  0);
        push(pw3,    pw3b,  64,  512,  0,    512,  0);
        push(uw,     uwb,   128, 1024, 0,    1024, 0);
        push(up,     upb,   64,  512,  0,    1024, 0);
        push(A_U,    AUb,   32,  256,  0,    1024, 0);
        push(A_V,    AVb,   32,  256,  0,    1024, 0);
        push(s_prev, FIN,   128, 2560, 0,    8192, 0);
        push(e_t,    FIN,   128, 2560, 1024, 8192, 0);
        push(c_t,    FIN,   64,  2560, 2048, 8192, 0);
        push(c_t,    ACAT,  64,  2048, 1024, 8192, 0);
        push(bnet_w, WCAT,  128, 2048, 1024, 1024, 0);
        ca.total = cum;
        multi_copy<<<dim3((cum + 255) / 256), blk, 0, stream>>>(ca);
    }

    // ---------- fused GEMM 1 (256²): fw1 (H) || gate (G) -> 256 blocks
    {
        GArgs ga;
        ga.d0 = GDesc{FIN, fw1b, fb1, nullptr, H, nullptr, nullptr, 2560, 1024, 1024, 2560, EP_NONE,    32, 0, 0};
        ga.d1 = GDesc{FIN, gwb,  gb,  nullptr, G, nullptr, nullptr, 2560, 1024, 1024, 2560, EP_SIGMOID, 32, 0, 0};
        ga.d2 = ga.d1; ga.s1 = 128; ga.s2 = 256;
        gemm_z<<<dim3(256), blk512, 0, stream>>>(ga);
    }
    ln1024<true><<<8192, blk, 0, stream>>>(H, fln_g, fln_b);

    // ---------- fused GEMM 2 (128²): fw2 (Z + ACAT col1536) || amod (ACAT) || A_base (WCAT)
    {
        GArgs ga;
        ga.d0 = GDesc{H,          fw2b,  fb2,     nullptr, Z,    nullptr, ACAT,    1024, 512,  512,  1024, EP_NONE,     64, 2048, 1536};
        ga.d1 = GDesc{FIN + 2048, amodb, amod_b,  w_prev,  ACAT, nullptr, nullptr, 2560, 2048, 1024, 512,  EP_TANH_MUL, 64, 0, 0};
        ga.d2 = GDesc{AUb,        AVb,   nullptr, A_diag,  WCAT, nullptr, nullptr, 256,  2048, 1024, 256,  EP_DIAG,     8, 0, 0};
        ga.s1 = 256; ga.s2 = 768;
        gemm_s<<<dim3(832), blk, 0, stream>>>(ga);
    }

    // ---------- batch 2: PIN = [p_prev || z || c_t] at FIN base
    {
        CArgs ca; unsigned cum = 0; int nd = 0;
        auto push = [&](const void* src, u16* dst, int cols8, int stride, int off,
                        int rows, int isbf) {
            cum += (unsigned)rows * cols8;
            ca.d[nd++] = CDesc{src, dst, cols8, stride, off, cum, isbf};
        };
        push(p_prev, FIN,  64, 1536, 0,    8192, 0);
        push(Z,      FIN,  64, 1536, 512,  8192, 1);
        push(c_t,    FIN,  64, 1536, 1024, 8192, 0);
        ca.total = cum;
        multi_copy<<<dim3((cum + 255) / 256), blk, 0, stream>>>(ca);
    }

    // ---------- fused GEMM 3 (256²): w_t (ACAT@WCAT^T) || pw1 (PIN) -> 256 blocks
    {
        GArgs ga;
        ga.d0 = GDesc{ACAT, WCAT, bnet_b, nullptr, W_bf, out_w,   nullptr, 2048, 1024, 1024, 2048, EP_NONE, 32, 0, 0};
        ga.d1 = GDesc{FIN,  pw1b, pb1,    nullptr, H,    nullptr, nullptr, 1536, 1024, 1024, 1536, EP_NONE, 32, 0, 0};
        ga.d2 = ga.d1; ga.s1 = 128; ga.s2 = 256;
        gemm_z<<<dim3(256), blk512, 0, stream>>>(ga);
    }
    ln1024<true><<<8192, blk, 0, stream>>>(H, pln_g, pln_b);

    // ---------- fused GEMM 4 (256²): pw2 (H -> Z, relu) || uw (W_bf -> WM) -> 192 blocks
    {
        GArgs ga;
        ga.d0 = GDesc{H,    pw2b, pb2,     nullptr, Z,  nullptr, nullptr, 1024, 512,  512,  1024, EP_RELU, 32, 0, 0};
        ga.d1 = GDesc{W_bf, uwb,  nullptr, nullptr, WM, nullptr, nullptr, 1024, 1024, 1024, 1024, EP_NONE, 32, 0, 0};
        ga.d2 = ga.d1; ga.s1 = 64; ga.s2 = 192;
        gemm_z<<<dim3(192), blk512, 0, stream>>>(ga);
    }

    // ---------- pw3 (128²): p_t = p_prev + tanh(Z@pw3^T + pb3) -> 256 blocks
    {
        GArgs ga;
        ga.d0 = GDesc{Z, pw3b, pb3, p_prev, P_bf, out_p, nullptr, 512, 512, 512, 512, EP_TANH_ADD, 64, 0, 0};
        ga.d1 = ga.d0; ga.d2 = ga.d0; ga.s1 = 256; ga.s2 = 256;
        gemm_s<<<dim3(256), blk, 0, stream>>>(ga);
    }

    // ---------- up (128²): pm = P_bf @ up^T -> 512 blocks
    {
        GArgs ga;
        ga.d0 = GDesc{P_bf, upb, nullptr, nullptr, PM, nullptr, nullptr, 512, 1024, 1024, 512, EP_NONE, 64, 0, 0};
        ga.d1 = ga.d0; ga.d2 = ga.d0; ga.s1 = 512; ga.s2 = 512;
        gemm_s<<<dim3(512), blk, 0, stream>>>(ga);
    }

    mix_ln<<<8192, blk, 0, stream>>>(s_prev, G, PM, WM, oln_g, oln_b, out_s);
}